// Round 1
// baseline (2527.906 us; speedup 1.0000x reference)
//
#include <hip/hip_runtime.h>
#include <hip/hip_bf16.h>

typedef __hip_bfloat16 bf16;
typedef short short8 __attribute__((ext_vector_type(8)));
typedef float f32x4 __attribute__((ext_vector_type(4)));

// static config
#define DIMC 512
#define HEADS_ 16
#define NTOK 65        // 64 window tokens + 1 time token
#define NWIN 64
#define NB 16
#define HID 2048
#define TOTROWS 66560  // 16*64*65
#define ATT_CHUNK_WB 128           // window-batches per attention chunk
#define ATT_CHUNK_ROWS (ATT_CHUNK_WB * NTOK)   // 8320
#define MLP_CHUNK_ROWS 8192

// ---------------- helpers ----------------

__device__ __forceinline__ int regidx(int p) { return p < 56 ? 0 : (p < 60 ? 1 : 2); }

__device__ __forceinline__ void row_stats512(float v0, float v1, int tid, float& m, float& rstd)
{
  float s = v0 + v1, ss = v0 * v0 + v1 * v1;
  #pragma unroll
  for (int o = 32; o > 0; o >>= 1) { s += __shfl_down(s, o); ss += __shfl_down(ss, o); }
  __shared__ float red[8];
  int lane = tid & 63, wv = tid >> 6;
  if (lane == 0) { red[wv] = s; red[4 + wv] = ss; }
  __syncthreads();
  if (tid == 0) {
    float S  = red[0] + red[1] + red[2] + red[3];
    float SS = red[4] + red[5] + red[6] + red[7];
    float mm = S * (1.0f / 512.0f);
    red[0] = mm;
    red[1] = rsqrtf(SS * (1.0f / 512.0f) - mm * mm + 1e-5f);
  }
  __syncthreads();
  m = red[0]; rstd = red[1];
}

// ---------------- small kernels ----------------

// t = silu(emb) @ W_emb + b_emb   (16 x 512)
__global__ __launch_bounds__(256) void time_emb_kernel(
    const float* __restrict__ emb, const float* __restrict__ W_emb,
    const float* __restrict__ b_emb, float* __restrict__ t)
{
  int b = blockIdx.x;
  int c = blockIdx.y * 256 + threadIdx.x;
  __shared__ float se[512];
  for (int k = threadIdx.x; k < 512; k += 256) {
    float e = emb[b * 512 + k];
    se[k] = e / (1.0f + expf(-e));
  }
  __syncthreads();
  float acc = b_emb[c];
  for (int k = 0; k < 512; ++k) acc += se[k] * W_emb[k * 512 + c];
  t[b * 512 + c] = acc;
}

// W (Kd x Nd) f32 -> Wt (Nd x Kd) bf16
__global__ void transpose_cast_kernel(const float* __restrict__ W, bf16* __restrict__ Wt,
                                      int Kd, int Nd)
{
  __shared__ float tile[32][33];
  int n0 = blockIdx.x * 32, k0 = blockIdx.y * 32;
  for (int r = threadIdx.y; r < 32; r += 8)
    tile[r][threadIdx.x] = W[(long)(k0 + r) * Nd + n0 + threadIdx.x];
  __syncthreads();
  for (int r = threadIdx.y; r < 32; r += 8)
    Wt[(long)(n0 + r) * Kd + k0 + threadIdx.x] = __float2bfloat16(tile[threadIdx.x][r]);
}

// LN1 + cyclic shift + window partition + time-token append -> xw bf16 (66560 x 512)
__global__ __launch_bounds__(256) void ln1_window_kernel(
    const float* __restrict__ x, const float* __restrict__ gamma,
    const float* __restrict__ beta, const float* __restrict__ t,
    bf16* __restrict__ xw)
{
  long r = blockIdx.x;                 // 0..66559
  int tid = threadIdx.x;
  int wb = (int)(r / NTOK), i = (int)(r % NTOK);
  int b = wb >> 6, w = wb & 63;
  bf16* out = xw + r * 512;
  if (i == 64) {
    const float* tr = t + b * 512;
    out[tid]       = __float2bfloat16(tr[tid]);
    out[tid + 256] = __float2bfloat16(tr[tid + 256]);
    return;                            // block-uniform branch
  }
  int wh = w >> 3, ww = w & 7, ih = i >> 3, iw = i & 7;
  int hsrc = ((wh * 8 + ih) + 4) & 63; // roll(-4): xs[h] = xn[(h+4)%64]
  int wsrc = ((ww * 8 + iw) + 4) & 63;
  const float* xr = x + ((long)b * 4096 + hsrc * 64 + wsrc) * 512;
  float v0 = xr[tid], v1 = xr[tid + 256];
  float m, rstd;
  row_stats512(v0, v1, tid, m, rstd);
  out[tid]       = __float2bfloat16((v0 - m) * rstd * gamma[tid] + beta[tid]);
  out[tid + 256] = __float2bfloat16((v1 - m) * rstd * gamma[tid + 256] + beta[tid + 256]);
}

// LN2 over x1 rows (65536 x 512) -> bf16
__global__ __launch_bounds__(256) void ln2_kernel(
    const float* __restrict__ x1, const float* __restrict__ gamma,
    const float* __restrict__ beta, bf16* __restrict__ out)
{
  long r = blockIdx.x;
  int tid = threadIdx.x;
  const float* xr = x1 + r * 512;
  float v0 = xr[tid], v1 = xr[tid + 256];
  float m, rstd;
  row_stats512(v0, v1, tid, m, rstd);
  out[r * 512 + tid]       = __float2bfloat16((v0 - m) * rstd * gamma[tid] + beta[tid]);
  out[r * 512 + tid + 256] = __float2bfloat16((v1 - m) * rstd * gamma[tid + 256] + beta[tid + 256]);
}

// ---------------- MFMA GEMM: C = A(MxK) @ Bt(NxK)^T + bias ----------------
// EPI 0: store bf16            (qkv)
// EPI 1: gelu -> bf16          (mlp hidden)
// EPI 2: proj: residual + window-reverse + unshift scatter into x1 (f32)
// EPI 3: f32 in-place add      (mlp out: outF[o] += v)
template<int EPI>
__global__ __launch_bounds__(256) void gemm_kernel(
    const bf16* __restrict__ A, const bf16* __restrict__ Bt,
    const float* __restrict__ bias, int N, int K,
    bf16* __restrict__ outB, float* __restrict__ outF,
    const float* __restrict__ xin, int rowOffset)
{
  __shared__ bf16 lA[128][40];
  __shared__ bf16 lB[128][40];
  const int tid = threadIdx.x;
  const int lane = tid & 63, wave = tid >> 6;
  const int wm = wave >> 1, wn = wave & 1;
  const long row0 = (long)blockIdx.y * 128;
  const int col0 = blockIdx.x * 128;
  f32x4 acc[4][4] = {};
  const int tr = tid >> 1, hc = (tid & 1) * 16;
  const int fr = lane & 15, fk = (lane >> 4) * 8;

  for (int kt = 0; kt < K; kt += 32) {
    const bf16* ga = A + (row0 + tr) * (long)K + kt + hc;
    const bf16* gb = Bt + (long)(col0 + tr) * K + kt + hc;
    *(short8*)&lA[tr][hc]     = ((const short8*)ga)[0];
    *(short8*)&lA[tr][hc + 8] = ((const short8*)ga)[1];
    *(short8*)&lB[tr][hc]     = ((const short8*)gb)[0];
    *(short8*)&lB[tr][hc + 8] = ((const short8*)gb)[1];
    __syncthreads();
    short8 af[4], bfr[4];
    #pragma unroll
    for (int mi = 0; mi < 4; ++mi) af[mi]  = *(const short8*)&lA[wm * 64 + mi * 16 + fr][fk];
    #pragma unroll
    for (int ni = 0; ni < 4; ++ni) bfr[ni] = *(const short8*)&lB[wn * 64 + ni * 16 + fr][fk];
    #pragma unroll
    for (int mi = 0; mi < 4; ++mi)
      #pragma unroll
      for (int ni = 0; ni < 4; ++ni)
        acc[mi][ni] = __builtin_amdgcn_mfma_f32_16x16x32_bf16(af[mi], bfr[ni], acc[mi][ni], 0, 0, 0);
    __syncthreads();
  }

  const int fg = lane >> 4;
  #pragma unroll
  for (int mi = 0; mi < 4; ++mi) {
    #pragma unroll
    for (int ni = 0; ni < 4; ++ni) {
      int cc = col0 + wn * 64 + ni * 16 + fr;
      float bs = bias[cc];
      #pragma unroll
      for (int j = 0; j < 4; ++j) {
        long rr = row0 + wm * 64 + mi * 16 + fg * 4 + j;   // local row
        float v = acc[mi][ni][j] + bs;
        if (EPI == 0) {
          outB[rr * N + cc] = __float2bfloat16(v);
        } else if (EPI == 1) {
          float g = 0.5f * v * (1.0f + erff(v * 0.70710678118654752f));
          outB[rr * N + cc] = __float2bfloat16(g);
        } else if (EPI == 2) {
          int grow = rowOffset + (int)rr;                  // global row in [0,66560)
          int ii = grow % NTOK;
          if (ii != 64) {
            int wb = grow / NTOK;
            int b = wb >> 6, w = wb & 63;
            int wh = w >> 3, ww = w & 7, ih = ii >> 3, iw = ii & 7;
            int hh   = ((wh * 8 + ih) + 4) & 63;           // roll(+4) reverse
            int wcol = ((ww * 8 + iw) + 4) & 63;
            long o = ((long)b * 4096 + hh * 64 + wcol) * 512 + cc;
            outF[o] = xin[o] + v;                          // x1 = shortcut + proj
          }
        } else { // EPI 3
          long o = rr * N + cc;
          outF[o] = outF[o] + v;                           // out = x1 + mlp
        }
      }
    }
  }
}

// ---------------- windowed attention (per window-batch, per head) ----------------
__global__ __launch_bounds__(256) void attn_kernel(
    const bf16* __restrict__ qkv, bf16* __restrict__ attnO,
    const float* __restrict__ btab, int wb0)
{
  __shared__ float lq[65][32], lk[65][32], lv[65][32];
  __shared__ float lS[65][66];
  const int lwb = blockIdx.x, h = blockIdx.y, tid = threadIdx.x;
  const int w = (wb0 + lwb) & 63;   // window index within image
  const float scale = 0.17677669529663687f; // 1/sqrt(32)
  const bf16* base = qkv + (long)lwb * 65 * 1536 + h * 32;
  for (int idx = tid; idx < 65 * 32; idx += 256) {
    int i = idx >> 5, d = idx & 31;
    const bf16* p = base + (long)i * 1536 + d;
    lq[i][d] = scale * __bfloat162float(p[0]);
    lk[i][d] = __bfloat162float(p[512]);
    lv[i][d] = __bfloat162float(p[1024]);
  }
  __syncthreads();
  const int wh = w >> 3, ww = w & 7;
  for (int idx = tid; idx < 65 * 65; idx += 256) {
    int i = idx / 65, j = idx - i * 65;
    const float* qa = lq[i];
    const float* ka = lk[j];
    float s = 0.0f;
    #pragma unroll
    for (int d = 0; d < 32; ++d) s += qa[d] * ka[d];
    if (i < 64 && j < 64) {
      int ih = i >> 3, iw = i & 7, jh = j >> 3, jw = j & 7;
      s += btab[((ih - jh + 7) * 15 + (iw - jw + 7)) * HEADS_ + h];
      int mi_ = 3 * regidx(wh * 8 + ih) + regidx(ww * 8 + iw);
      int mj_ = 3 * regidx(wh * 8 + jh) + regidx(ww * 8 + jw);
      if (mi_ != mj_) s -= 100.0f;
    }
    lS[i][j] = s;
  }
  __syncthreads();
  if (tid < 65) {
    float mx = -1e30f;
    for (int j = 0; j < 65; ++j) mx = fmaxf(mx, lS[tid][j]);
    float sum = 0.0f;
    for (int j = 0; j < 65; ++j) { float e = expf(lS[tid][j] - mx); lS[tid][j] = e; sum += e; }
    float inv = 1.0f / sum;
    for (int j = 0; j < 65; ++j) lS[tid][j] *= inv;
  }
  __syncthreads();
  for (int idx = tid; idx < 65 * 8; idx += 256) {
    int i = idx >> 3, d4 = (idx & 7) * 4;
    float o0 = 0, o1 = 0, o2 = 0, o3 = 0;
    for (int j = 0; j < 65; ++j) {
      float p = lS[i][j];
      o0 += p * lv[j][d4 + 0];
      o1 += p * lv[j][d4 + 1];
      o2 += p * lv[j][d4 + 2];
      o3 += p * lv[j][d4 + 3];
    }
    bf16* op = attnO + (long)(lwb * 65 + i) * 512 + h * 32 + d4;
    op[0] = __float2bfloat16(o0); op[1] = __float2bfloat16(o1);
    op[2] = __float2bfloat16(o2); op[3] = __float2bfloat16(o3);
  }
}

// ---------------- host ----------------

extern "C" void kernel_launch(void* const* d_in, const int* in_sizes, int n_in,
                              void* d_out, int out_size, void* d_ws, size_t ws_size,
                              hipStream_t stream)
{
  const float* x      = (const float*)d_in[0];
  const float* emb    = (const float*)d_in[1];
  const float* gamma1 = (const float*)d_in[2];
  const float* beta1  = (const float*)d_in[3];
  const float* W_emb  = (const float*)d_in[4];
  const float* b_emb  = (const float*)d_in[5];
  const float* W_qkv  = (const float*)d_in[6];
  const float* b_qkv  = (const float*)d_in[7];
  const float* btab   = (const float*)d_in[8];
  const float* W_proj = (const float*)d_in[9];
  const float* b_proj = (const float*)d_in[10];
  const float* gamma2 = (const float*)d_in[11];
  const float* beta2  = (const float*)d_in[12];
  const float* W1     = (const float*)d_in[13];
  const float* b1     = (const float*)d_in[14];
  const float* W2     = (const float*)d_in[15];
  const float* b2     = (const float*)d_in[16];
  float* out = (float*)d_out;

  char* ws = (char*)d_ws;
  size_t off = 0;
  auto alloc = [&](size_t bytes) -> char* {
    char* p = ws + off;
    off += (bytes + 255) & ~(size_t)255;
    return p;
  };
  bf16* wt_qkv  = (bf16*)alloc((size_t)1536 * 512 * 2);
  bf16* wt_proj = (bf16*)alloc((size_t)512 * 512 * 2);
  bf16* wt1     = (bf16*)alloc((size_t)2048 * 512 * 2);
  bf16* wt2     = (bf16*)alloc((size_t)512 * 2048 * 2);
  float* tvec   = (float*)alloc((size_t)16 * 512 * 4);
  bf16* xw      = (bf16*)alloc((size_t)TOTROWS * 512 * 2);
  bf16* qkv_c   = (bf16*)alloc((size_t)ATT_CHUNK_ROWS * 1536 * 2);
  bf16* attnO_c = (bf16*)alloc((size_t)ATT_CHUNK_ROWS * 512 * 2);
  bf16* ln2b    = (bf16*)alloc((size_t)65536 * 512 * 2);
  bf16* h_c     = (bf16*)alloc((size_t)MLP_CHUNK_ROWS * 2048 * 2);
  (void)ws_size; (void)n_in; (void)in_sizes; (void)out_size;

  // weight prep
  transpose_cast_kernel<<<dim3(1536 / 32, 512 / 32), dim3(32, 8), 0, stream>>>(W_qkv, wt_qkv, 512, 1536);
  transpose_cast_kernel<<<dim3(512 / 32, 512 / 32),  dim3(32, 8), 0, stream>>>(W_proj, wt_proj, 512, 512);
  transpose_cast_kernel<<<dim3(2048 / 32, 512 / 32), dim3(32, 8), 0, stream>>>(W1, wt1, 512, 2048);
  transpose_cast_kernel<<<dim3(512 / 32, 2048 / 32), dim3(32, 8), 0, stream>>>(W2, wt2, 2048, 512);
  time_emb_kernel<<<dim3(16, 2), 256, 0, stream>>>(emb, W_emb, b_emb, tvec);

  // LN1 + shift + window partition + time token
  ln1_window_kernel<<<TOTROWS, 256, 0, stream>>>(x, gamma1, beta1, tvec, xw);

  // attention path, chunked over window-batches
  for (int ac = 0; ac < 8; ++ac) {
    long r0 = (long)ac * ATT_CHUNK_ROWS;
    gemm_kernel<0><<<dim3(1536 / 128, ATT_CHUNK_ROWS / 128), 256, 0, stream>>>(
        xw + r0 * 512, wt_qkv, b_qkv, 1536, 512, qkv_c, nullptr, nullptr, 0);
    attn_kernel<<<dim3(ATT_CHUNK_WB, HEADS_), 256, 0, stream>>>(
        qkv_c, attnO_c, btab, ac * ATT_CHUNK_WB);
    gemm_kernel<2><<<dim3(512 / 128, ATT_CHUNK_ROWS / 128), 256, 0, stream>>>(
        attnO_c, wt_proj, b_proj, 512, 512, nullptr, out, x, (int)r0);
  }

  // LN2
  ln2_kernel<<<65536, 256, 0, stream>>>(out, gamma2, beta2, ln2b);

  // MLP, chunked over rows
  for (int mc = 0; mc < 8; ++mc) {
    long r0 = (long)mc * MLP_CHUNK_ROWS;
    gemm_kernel<1><<<dim3(2048 / 128, MLP_CHUNK_ROWS / 128), 256, 0, stream>>>(
        ln2b + r0 * 512, wt1, b1, 2048, 512, h_c, nullptr, nullptr, 0);
    gemm_kernel<3><<<dim3(512 / 128, MLP_CHUNK_ROWS / 128), 256, 0, stream>>>(
        h_c, wt2, b2, 512, 2048, nullptr, out + r0 * 512, nullptr, 0);
  }
}

// Round 2
// 1617.748 us; speedup vs baseline: 1.5626x; 1.5626x over previous
//
#include <hip/hip_runtime.h>
#include <hip/hip_bf16.h>

typedef __hip_bfloat16 bf16;
typedef short short8 __attribute__((ext_vector_type(8)));
typedef float f32x4 __attribute__((ext_vector_type(4)));

// static config
#define DIMC 512
#define HEADS_ 16
#define NTOK 65        // 64 window tokens + 1 time token
#define NWIN 64
#define NB 16
#define HID 2048
#define TOTROWS 66560  // 16*64*65
#define ATT_CHUNK_WB 128                      // window-batches per attention chunk
#define ATT_CHUNK_ROWS (ATT_CHUNK_WB * NTOK)  // 8320
#define MLP_CHUNK_ROWS 16384

// ---------------- helpers ----------------

__device__ __forceinline__ int regidx(int p) { return p < 56 ? 0 : (p < 60 ? 1 : 2); }

__device__ __forceinline__ float b2f(short s) {
  unsigned int u = ((unsigned int)(unsigned short)s) << 16;
  float f; __builtin_memcpy(&f, &u, 4); return f;
}
__device__ __forceinline__ short f2s(float f) {
  bf16 b = __float2bfloat16(f);
  short s; __builtin_memcpy(&s, &b, 2); return s;
}

// async global->LDS, 16B per lane; LDS dest is wave-uniform base + lane*16
__device__ __forceinline__ void async_lds16(const bf16* g, bf16* l) {
#if __has_builtin(__builtin_amdgcn_global_load_lds)
  __builtin_amdgcn_global_load_lds(
      (const __attribute__((address_space(1))) unsigned int*)g,
      (__attribute__((address_space(3))) unsigned int*)l,
      16, 0, 0);
#else
  // equivalent fallback through VGPRs: lane writes its own 16B slot
  int lane = threadIdx.x & 63;
  *(short8*)((char*)l + lane * 16) = *(const short8*)g;
#endif
}

__device__ __forceinline__ void row_stats512(float v0, float v1, int tid, float& m, float& rstd)
{
  float s = v0 + v1, ss = v0 * v0 + v1 * v1;
  #pragma unroll
  for (int o = 32; o > 0; o >>= 1) { s += __shfl_down(s, o); ss += __shfl_down(ss, o); }
  __shared__ float red[8];
  int lane = tid & 63, wv = tid >> 6;
  if (lane == 0) { red[wv] = s; red[4 + wv] = ss; }
  __syncthreads();
  if (tid == 0) {
    float S  = red[0] + red[1] + red[2] + red[3];
    float SS = red[4] + red[5] + red[6] + red[7];
    float mm = S * (1.0f / 512.0f);
    red[0] = mm;
    red[1] = rsqrtf(SS * (1.0f / 512.0f) - mm * mm + 1e-5f);
  }
  __syncthreads();
  m = red[0]; rstd = red[1];
}

// ---------------- small kernels ----------------

// t = silu(emb) @ W_emb + b_emb   (16 x 512)
__global__ __launch_bounds__(256) void time_emb_kernel(
    const float* __restrict__ emb, const float* __restrict__ W_emb,
    const float* __restrict__ b_emb, float* __restrict__ t)
{
  int b = blockIdx.x;
  int c = blockIdx.y * 256 + threadIdx.x;
  __shared__ float se[512];
  for (int k = threadIdx.x; k < 512; k += 256) {
    float e = emb[b * 512 + k];
    se[k] = e / (1.0f + expf(-e));
  }
  __syncthreads();
  float acc = b_emb[c];
  for (int k = 0; k < 512; ++k) acc += se[k] * W_emb[k * 512 + c];
  t[b * 512 + c] = acc;
}

// W (Kd x Nd) f32 -> Wt (Nd x Kd) bf16
__global__ void transpose_cast_kernel(const float* __restrict__ W, bf16* __restrict__ Wt,
                                      int Kd, int Nd)
{
  __shared__ float tile[32][33];
  int n0 = blockIdx.x * 32, k0 = blockIdx.y * 32;
  for (int r = threadIdx.y; r < 32; r += 8)
    tile[r][threadIdx.x] = W[(long)(k0 + r) * Nd + n0 + threadIdx.x];
  __syncthreads();
  for (int r = threadIdx.y; r < 32; r += 8)
    Wt[(long)(n0 + r) * Kd + k0 + threadIdx.x] = __float2bfloat16(tile[threadIdx.x][r]);
}

// LN1 + cyclic shift + window partition + time-token append -> xw bf16 (66560 x 512)
__global__ __launch_bounds__(256) void ln1_window_kernel(
    const float* __restrict__ x, const float* __restrict__ gamma,
    const float* __restrict__ beta, const float* __restrict__ t,
    bf16* __restrict__ xw)
{
  long r = blockIdx.x;                 // 0..66559
  int tid = threadIdx.x;
  int wb = (int)(r / NTOK), i = (int)(r % NTOK);
  int b = wb >> 6, w = wb & 63;
  bf16* out = xw + r * 512;
  if (i == 64) {
    const float* tr = t + b * 512;
    out[tid]       = __float2bfloat16(tr[tid]);
    out[tid + 256] = __float2bfloat16(tr[tid + 256]);
    return;                            // block-uniform branch
  }
  int wh = w >> 3, ww = w & 7, ih = i >> 3, iw = i & 7;
  int hsrc = ((wh * 8 + ih) + 4) & 63; // roll(-4): xs[h] = xn[(h+4)%64]
  int wsrc = ((ww * 8 + iw) + 4) & 63;
  const float* xr = x + ((long)b * 4096 + hsrc * 64 + wsrc) * 512;
  float v0 = xr[tid], v1 = xr[tid + 256];
  float m, rstd;
  row_stats512(v0, v1, tid, m, rstd);
  out[tid]       = __float2bfloat16((v0 - m) * rstd * gamma[tid] + beta[tid]);
  out[tid + 256] = __float2bfloat16((v1 - m) * rstd * gamma[tid + 256] + beta[tid + 256]);
}

// LN2 over x1 rows (65536 x 512) -> bf16
__global__ __launch_bounds__(256) void ln2_kernel(
    const float* __restrict__ x1, const float* __restrict__ gamma,
    const float* __restrict__ beta, bf16* __restrict__ out)
{
  long r = blockIdx.x;
  int tid = threadIdx.x;
  const float* xr = x1 + r * 512;
  float v0 = xr[tid], v1 = xr[tid + 256];
  float m, rstd;
  row_stats512(v0, v1, tid, m, rstd);
  out[r * 512 + tid]       = __float2bfloat16((v0 - m) * rstd * gamma[tid] + beta[tid]);
  out[r * 512 + tid + 256] = __float2bfloat16((v1 - m) * rstd * gamma[tid + 256] + beta[tid + 256]);
}

// ---------------- MFMA GEMM (m97 structure): C = A(MxK) @ Bt(NxK)^T + bias ----------------
// Linear LDS [128][32] bf16, staged via global_load_lds width-16.
// EPI 0: store bf16            (qkv)
// EPI 1: gelu -> bf16          (mlp hidden)
// EPI 2: proj: residual + window-reverse + unshift scatter into x1 (f32)
// EPI 3: f32 in-place add      (mlp out: outF[o] += v)
template<int EPI>
__global__ __launch_bounds__(256) void gemm_kernel(
    const bf16* __restrict__ A, const bf16* __restrict__ Bt,
    const float* __restrict__ bias, int N, int K,
    bf16* __restrict__ outB, float* __restrict__ outF,
    const float* __restrict__ xin, int rowOffset)
{
  __shared__ bf16 lA[128 * 32];
  __shared__ bf16 lB[128 * 32];
  const int tid = threadIdx.x;
  const int lane = tid & 63, wave = tid >> 6;
  const int wm = wave >> 1, wn = wave & 1;
  const long row0 = (long)blockIdx.y * 128;
  const int col0 = blockIdx.x * 128;
  f32x4 acc[4][4] = {};
  const int fr = lane & 15, fk = (lane >> 4) * 8;

  // staging geometry: instruction (q in {0,1}) of wave wv covers rows [(q*4+wv)*16, +16)
  const int lrow = lane >> 2;          // sub-row within 16-row group
  const int koff = (lane & 3) * 8;     // k-element offset (8 elems = 16B)
  const bf16* gA = A + (row0 + lrow) * (long)K + koff;
  const bf16* gB = Bt + ((long)col0 + lrow) * K + koff;
  const int rb0 = wave * 16;           // q=0 row block
  const int rb1 = 64 + wave * 16;      // q=1 row block
  bf16* lA0 = lA + rb0 * 32; bf16* lA1 = lA + rb1 * 32;
  bf16* lB0 = lB + rb0 * 32; bf16* lB1 = lB + rb1 * 32;
  const long sA0 = (long)rb0 * K, sA1 = (long)rb1 * K;

  for (int kt = 0; kt < K; kt += 32) {
    async_lds16(gA + sA0 + kt, lA0);
    async_lds16(gA + sA1 + kt, lA1);
    async_lds16(gB + sA0 + kt, lB0);
    async_lds16(gB + sA1 + kt, lB1);
    __syncthreads();
    short8 af[4], bfr[4];
    #pragma unroll
    for (int mi = 0; mi < 4; ++mi) af[mi]  = *(const short8*)&lA[(wm * 64 + mi * 16 + fr) * 32 + fk];
    #pragma unroll
    for (int ni = 0; ni < 4; ++ni) bfr[ni] = *(const short8*)&lB[(wn * 64 + ni * 16 + fr) * 32 + fk];
    #pragma unroll
    for (int mi = 0; mi < 4; ++mi)
      #pragma unroll
      for (int ni = 0; ni < 4; ++ni)
        acc[mi][ni] = __builtin_amdgcn_mfma_f32_16x16x32_bf16(af[mi], bfr[ni], acc[mi][ni], 0, 0, 0);
    __syncthreads();
  }

  const int fg = lane >> 4;
  #pragma unroll
  for (int mi = 0; mi < 4; ++mi) {
    #pragma unroll
    for (int ni = 0; ni < 4; ++ni) {
      int cc = col0 + wn * 64 + ni * 16 + fr;
      float bs = bias[cc];
      #pragma unroll
      for (int j = 0; j < 4; ++j) {
        long rr = row0 + wm * 64 + mi * 16 + fg * 4 + j;   // local row
        float v = acc[mi][ni][j] + bs;
        if (EPI == 0) {
          outB[rr * N + cc] = __float2bfloat16(v);
        } else if (EPI == 1) {
          float g = 0.5f * v * (1.0f + erff(v * 0.70710678118654752f));
          outB[rr * N + cc] = __float2bfloat16(g);
        } else if (EPI == 2) {
          int grow = rowOffset + (int)rr;                  // global row in [0,66560)
          int ii = grow % NTOK;
          if (ii != 64) {
            int wb = grow / NTOK;
            int b = wb >> 6, w = wb & 63;
            int wh = w >> 3, ww = w & 7, ih = ii >> 3, iw = ii & 7;
            int hh   = ((wh * 8 + ih) + 4) & 63;           // roll(+4) reverse
            int wcol = ((ww * 8 + iw) + 4) & 63;
            long o = ((long)b * 4096 + hh * 64 + wcol) * 512 + cc;
            outF[o] = xin[o] + v;                          // x1 = shortcut + proj
          }
        } else { // EPI 3
          long o = rr * N + cc;
          outF[o] = outF[o] + v;                           // out = x1 + mlp
        }
      }
    }
  }
}

// ---------------- windowed attention (per window-batch, per head) ----------------
// 4 threads per row: thread (i = tid>>2, s = tid&3). Q in registers, K/V f32 in
// LDS with pad-36 rows (16B aligned, conflict-free float4 reads).
__global__ __launch_bounds__(256) void attn_kernel(
    const bf16* __restrict__ qkv, bf16* __restrict__ attnO,
    const float* __restrict__ btab, int wb0)
{
  __shared__ float lk[65][36], lv[65][36];
  __shared__ float lS[65][66];
  const int lwb = blockIdx.x, h = blockIdx.y, tid = threadIdx.x;
  const int w = (wb0 + lwb) & 63;
  const float scale = 0.17677669529663687f; // 1/sqrt(32)
  const bf16* base = qkv + (long)lwb * 65 * 1536 + h * 32;

  // stage K, V (bf16 -> f32)
  for (int idx = tid; idx < 65 * 4; idx += 256) {
    int i = idx >> 2, c = (idx & 3) * 8;
    short8 kk = *(const short8*)(base + (long)i * 1536 + 512 + c);
    short8 vv = *(const short8*)(base + (long)i * 1536 + 1024 + c);
    #pragma unroll
    for (int e = 0; e < 8; ++e) {
      lk[i][c + e] = b2f(kk[e]);
      lv[i][c + e] = b2f(vv[e]);
    }
  }
  // Q row for this thread group -> registers (scaled)
  const int iq = tid >> 2, s4 = tid & 3;
  float qreg[32];
  {
    const bf16* qp = base + (long)iq * 1536;
    #pragma unroll
    for (int c = 0; c < 4; ++c) {
      short8 qq = *(const short8*)(qp + c * 8);
      #pragma unroll
      for (int e = 0; e < 8; ++e) qreg[c * 8 + e] = scale * b2f(qq[e]);
    }
  }
  __syncthreads();

  // QK^T + bias + mask
  const int wh = w >> 3, ww = w & 7;
  const int ih = iq >> 3, iwq = iq & 7;
  const int miq = 3 * regidx(wh * 8 + ih) + regidx(ww * 8 + iwq);
  for (int j = s4; j < 65; j += 4) {
    const float* kr = lk[j];
    float s = 0.0f;
    #pragma unroll
    for (int d = 0; d < 32; d += 4) {
      f32x4 kv4 = *(const f32x4*)&kr[d];
      s += qreg[d] * kv4[0] + qreg[d + 1] * kv4[1] + qreg[d + 2] * kv4[2] + qreg[d + 3] * kv4[3];
    }
    if (j < 64) {
      int jh = j >> 3, jw = j & 7;
      s += btab[((ih - jh + 7) * 15 + (iwq - jw + 7)) * HEADS_ + h];
      int mj_ = 3 * regidx(wh * 8 + jh) + regidx(ww * 8 + jw);
      if (miq != mj_) s -= 100.0f;
    }
    lS[iq][j] = s;
  }
  // row 64 (time token): handled by threads 0..3, no bias/mask
  if (tid < 4) {
    float q64[32];
    const bf16* qp = base + (long)64 * 1536;
    #pragma unroll
    for (int c = 0; c < 4; ++c) {
      short8 qq = *(const short8*)(qp + c * 8);
      #pragma unroll
      for (int e = 0; e < 8; ++e) q64[c * 8 + e] = scale * b2f(qq[e]);
    }
    for (int j = tid; j < 65; j += 4) {
      const float* kr = lk[j];
      float s = 0.0f;
      #pragma unroll
      for (int d = 0; d < 32; d += 4) {
        f32x4 kv4 = *(const f32x4*)&kr[d];
        s += q64[d] * kv4[0] + q64[d + 1] * kv4[1] + q64[d + 2] * kv4[2] + q64[d + 3] * kv4[3];
      }
      lS[64][j] = s;
    }
  }
  __syncthreads();

  // softmax, 4 threads per row
  {
    float mx = -1e30f;
    for (int j = s4; j < 65; j += 4) mx = fmaxf(mx, lS[iq][j]);
    mx = fmaxf(mx, __shfl_xor(mx, 1));
    mx = fmaxf(mx, __shfl_xor(mx, 2));
    float sum = 0.0f;
    for (int j = s4; j < 65; j += 4) { float e = __expf(lS[iq][j] - mx); lS[iq][j] = e; sum += e; }
    sum += __shfl_xor(sum, 1);
    sum += __shfl_xor(sum, 2);
    float inv = 1.0f / sum;
    for (int j = s4; j < 65; j += 4) lS[iq][j] *= inv;
  }
  if (tid < 4) {
    float mx = -1e30f;
    for (int j = tid; j < 65; j += 4) mx = fmaxf(mx, lS[64][j]);
    mx = fmaxf(mx, __shfl_xor(mx, 1));
    mx = fmaxf(mx, __shfl_xor(mx, 2));
    float sum = 0.0f;
    for (int j = tid; j < 65; j += 4) { float e = __expf(lS[64][j] - mx); lS[64][j] = e; sum += e; }
    sum += __shfl_xor(sum, 1);
    sum += __shfl_xor(sum, 2);
    float inv = 1.0f / sum;
    for (int j = tid; j < 65; j += 4) lS[64][j] *= inv;
  }
  __syncthreads();

  // PV: thread (iq, s4) computes out[iq][s4*8 .. s4*8+7]
  const int d0 = s4 * 8;
  {
    f32x4 o0 = {0, 0, 0, 0}, o1 = {0, 0, 0, 0};
    for (int j = 0; j < 65; ++j) {
      float p = lS[iq][j];
      f32x4 va = *(const f32x4*)&lv[j][d0];
      f32x4 vb = *(const f32x4*)&lv[j][d0 + 4];
      o0 += p * va;
      o1 += p * vb;
    }
    short8 os;
    #pragma unroll
    for (int e = 0; e < 4; ++e) { os[e] = f2s(o0[e]); os[4 + e] = f2s(o1[e]); }
    *(short8*)(attnO + (long)(lwb * 65 + iq) * 512 + h * 32 + d0) = os;
  }
  if (tid < 4) {
    int dd = tid * 8;
    f32x4 o0 = {0, 0, 0, 0}, o1 = {0, 0, 0, 0};
    for (int j = 0; j < 65; ++j) {
      float p = lS[64][j];
      f32x4 va = *(const f32x4*)&lv[j][dd];
      f32x4 vb = *(const f32x4*)&lv[j][dd + 4];
      o0 += p * va;
      o1 += p * vb;
    }
    short8 os;
    #pragma unroll
    for (int e = 0; e < 4; ++e) { os[e] = f2s(o0[e]); os[4 + e] = f2s(o1[e]); }
    *(short8*)(attnO + (long)(lwb * 65 + 64) * 512 + h * 32 + dd) = os;
  }
}

// ---------------- host ----------------

extern "C" void kernel_launch(void* const* d_in, const int* in_sizes, int n_in,
                              void* d_out, int out_size, void* d_ws, size_t ws_size,
                              hipStream_t stream)
{
  const float* x      = (const float*)d_in[0];
  const float* emb    = (const float*)d_in[1];
  const float* gamma1 = (const float*)d_in[2];
  const float* beta1  = (const float*)d_in[3];
  const float* W_emb  = (const float*)d_in[4];
  const float* b_emb  = (const float*)d_in[5];
  const float* W_qkv  = (const float*)d_in[6];
  const float* b_qkv  = (const float*)d_in[7];
  const float* btab   = (const float*)d_in[8];
  const float* W_proj = (const float*)d_in[9];
  const float* b_proj = (const float*)d_in[10];
  const float* gamma2 = (const float*)d_in[11];
  const float* beta2  = (const float*)d_in[12];
  const float* W1     = (const float*)d_in[13];
  const float* b1     = (const float*)d_in[14];
  const float* W2     = (const float*)d_in[15];
  const float* b2     = (const float*)d_in[16];
  float* out = (float*)d_out;

  char* ws = (char*)d_ws;
  size_t off = 0;
  auto alloc = [&](size_t bytes) -> char* {
    char* p = ws + off;
    off += (bytes + 255) & ~(size_t)255;
    return p;
  };
  bf16* wt_qkv  = (bf16*)alloc((size_t)1536 * 512 * 2);
  bf16* wt_proj = (bf16*)alloc((size_t)512 * 512 * 2);
  bf16* wt1     = (bf16*)alloc((size_t)2048 * 512 * 2);
  bf16* wt2     = (bf16*)alloc((size_t)512 * 2048 * 2);
  float* tvec   = (float*)alloc((size_t)16 * 512 * 4);
  // region A: xw (66560x512 bf16) ... later reused as ln2b (65536x512 bf16)
  char* regionA = alloc((size_t)TOTROWS * 512 * 2);
  bf16* xw   = (bf16*)regionA;
  bf16* ln2b = (bf16*)regionA;
  bf16* qkv_c = (bf16*)alloc((size_t)ATT_CHUNK_ROWS * 1536 * 2);
  // region B: attnO (66560x512 bf16) ... later reused as h_c (16384x2048 bf16)
  char* regionB = alloc((size_t)TOTROWS * 512 * 2);
  bf16* attnO = (bf16*)regionB;
  bf16* h_c   = (bf16*)regionB;
  (void)ws_size; (void)n_in; (void)in_sizes; (void)out_size;

  // weight prep
  transpose_cast_kernel<<<dim3(1536 / 32, 512 / 32), dim3(32, 8), 0, stream>>>(W_qkv, wt_qkv, 512, 1536);
  transpose_cast_kernel<<<dim3(512 / 32, 512 / 32),  dim3(32, 8), 0, stream>>>(W_proj, wt_proj, 512, 512);
  transpose_cast_kernel<<<dim3(2048 / 32, 512 / 32), dim3(32, 8), 0, stream>>>(W1, wt1, 512, 2048);
  transpose_cast_kernel<<<dim3(512 / 32, 2048 / 32), dim3(32, 8), 0, stream>>>(W2, wt2, 2048, 512);
  time_emb_kernel<<<dim3(16, 2), 256, 0, stream>>>(emb, W_emb, b_emb, tvec);

  // LN1 + shift + window partition + time token
  ln1_window_kernel<<<TOTROWS, 256, 0, stream>>>(x, gamma1, beta1, tvec, xw);

  // attention path: qkv + attn chunked, attnO accumulated full
  for (int ac = 0; ac < 8; ++ac) {
    long r0 = (long)ac * ATT_CHUNK_ROWS;
    gemm_kernel<0><<<dim3(1536 / 128, ATT_CHUNK_ROWS / 128), 256, 0, stream>>>(
        xw + r0 * 512, wt_qkv, b_qkv, 1536, 512, qkv_c, nullptr, nullptr, 0);
    attn_kernel<<<dim3(ATT_CHUNK_WB, HEADS_), 256, 0, stream>>>(
        qkv_c, attnO + r0 * 512, btab, ac * ATT_CHUNK_WB);
  }
  // proj: single dispatch over all rows (residual + window-reverse fused)
  gemm_kernel<2><<<dim3(512 / 128, TOTROWS / 128), 256, 0, stream>>>(
      attnO, wt_proj, b_proj, 512, 512, nullptr, out, x, 0);

  // LN2 (reuses region A; xw is dead)
  ln2_kernel<<<65536, 256, 0, stream>>>(out, gamma2, beta2, ln2b);

  // MLP, 4 chunks of 16384 rows (h_c reuses region B; attnO is dead)
  for (int mc = 0; mc < 4; ++mc) {
    long r0 = (long)mc * MLP_CHUNK_ROWS;
    gemm_kernel<1><<<dim3(2048 / 128, MLP_CHUNK_ROWS / 128), 256, 0, stream>>>(
        ln2b + r0 * 512, wt1, b1, 2048, 512, h_c, nullptr, nullptr, 0);
    gemm_kernel<3><<<dim3(512 / 128, MLP_CHUNK_ROWS / 128), 256, 0, stream>>>(
        h_c, wt2, b2, 512, 2048, nullptr, out + r0 * 512, nullptr, 0);
  }
}

// Round 3
// 1358.280 us; speedup vs baseline: 1.8611x; 1.1910x over previous
//
#include <hip/hip_runtime.h>
#include <hip/hip_bf16.h>

typedef __hip_bfloat16 bf16;
typedef short short8 __attribute__((ext_vector_type(8)));
typedef float f32x4 __attribute__((ext_vector_type(4)));

// static config
#define DIMC 512
#define HEADS_ 16
#define NTOK 65        // 64 window tokens + 1 time token
#define NWIN 64
#define NB 16
#define HID 2048
#define TOTROWS 66560  // 16*64*65
#define ATT_CHUNK_WB 128                      // window-batches per attention chunk
#define ATT_CHUNK_ROWS (ATT_CHUNK_WB * NTOK)  // 8320
#define MLP_CHUNK_ROWS 16384

// ---------------- helpers ----------------

__device__ __forceinline__ int regidx(int p) { return p < 56 ? 0 : (p < 60 ? 1 : 2); }

__device__ __forceinline__ float b2f(short s) {
  unsigned int u = ((unsigned int)(unsigned short)s) << 16;
  float f; __builtin_memcpy(&f, &u, 4); return f;
}
__device__ __forceinline__ short f2s(float f) {
  bf16 b = __float2bfloat16(f);
  short s; __builtin_memcpy(&s, &b, 2); return s;
}

// async global->LDS, 16B per lane; LDS dest is wave-uniform base + lane*16
__device__ __forceinline__ void async_lds16(const bf16* g, bf16* l) {
#if __has_builtin(__builtin_amdgcn_global_load_lds)
  __builtin_amdgcn_global_load_lds(
      (const __attribute__((address_space(1))) unsigned int*)g,
      (__attribute__((address_space(3))) unsigned int*)l,
      16, 0, 0);
#else
  int lane = threadIdx.x & 63;
  *(short8*)((char*)l + lane * 16) = *(const short8*)g;
#endif
}

// per-wave LN stats over 512 elems (8 per lane)
__device__ __forceinline__ void wave_stats512(const float* v, float& m, float& rstd)
{
  float s = 0.0f, ss = 0.0f;
  #pragma unroll
  for (int e = 0; e < 8; ++e) { s += v[e]; ss += v[e] * v[e]; }
  #pragma unroll
  for (int o = 1; o < 64; o <<= 1) { s += __shfl_xor(s, o); ss += __shfl_xor(ss, o); }
  m = s * (1.0f / 512.0f);
  rstd = rsqrtf(ss * (1.0f / 512.0f) - m * m + 1e-5f);
}

// ---------------- small kernels ----------------

// t = silu(emb) @ W_emb + b_emb   (16 x 512)
__global__ __launch_bounds__(256) void time_emb_kernel(
    const float* __restrict__ emb, const float* __restrict__ W_emb,
    const float* __restrict__ b_emb, float* __restrict__ t)
{
  int b = blockIdx.x;
  int c = blockIdx.y * 256 + threadIdx.x;
  __shared__ float se[512];
  for (int k = threadIdx.x; k < 512; k += 256) {
    float e = emb[b * 512 + k];
    se[k] = e / (1.0f + expf(-e));
  }
  __syncthreads();
  float acc = b_emb[c];
  for (int k = 0; k < 512; ++k) acc += se[k] * W_emb[k * 512 + c];
  t[b * 512 + c] = acc;
}

// W (Kd x Nd) f32 -> Wt (Nd x Kd) bf16
__global__ void transpose_cast_kernel(const float* __restrict__ W, bf16* __restrict__ Wt,
                                      int Kd, int Nd)
{
  __shared__ float tile[32][33];
  int n0 = blockIdx.x * 32, k0 = blockIdx.y * 32;
  for (int r = threadIdx.y; r < 32; r += 8)
    tile[r][threadIdx.x] = W[(long)(k0 + r) * Nd + n0 + threadIdx.x];
  __syncthreads();
  for (int r = threadIdx.y; r < 32; r += 8)
    Wt[(long)(n0 + r) * Kd + k0 + threadIdx.x] = __float2bfloat16(tile[threadIdx.x][r]);
}

// LN1 + cyclic shift + window partition + time-token append -> xw bf16 (66560 x 512)
// one WAVE per row
__global__ __launch_bounds__(256) void ln1_window_kernel(
    const float* __restrict__ x, const float* __restrict__ gamma,
    const float* __restrict__ beta, const float* __restrict__ t,
    bf16* __restrict__ xw)
{
  long r = (long)blockIdx.x * 4 + (threadIdx.x >> 6);   // 0..66559
  int lane = threadIdx.x & 63;
  int wb = (int)(r / NTOK), i = (int)(r % NTOK);
  int b = wb >> 6, w = wb & 63;
  bf16* out = xw + r * 512 + lane * 8;
  if (i == 64) {                        // time token (wave-uniform branch)
    const float* tr = t + b * 512 + lane * 8;
    short8 o;
    #pragma unroll
    for (int e = 0; e < 8; ++e) o[e] = f2s(tr[e]);
    *(short8*)out = o;
    return;
  }
  int wh = w >> 3, ww = w & 7, ih = i >> 3, iw = i & 7;
  int hsrc = ((wh * 8 + ih) + 4) & 63;  // roll(-4)
  int wsrc = ((ww * 8 + iw) + 4) & 63;
  const float* xr = x + ((long)b * 4096 + hsrc * 64 + wsrc) * 512 + lane * 8;
  float v[8];
  *(f32x4*)&v[0] = *(const f32x4*)xr;
  *(f32x4*)&v[4] = *(const f32x4*)(xr + 4);
  float m, rstd;
  wave_stats512(v, m, rstd);
  const float* g = gamma + lane * 8;
  const float* bt = beta + lane * 8;
  short8 o;
  #pragma unroll
  for (int e = 0; e < 8; ++e) o[e] = f2s((v[e] - m) * rstd * g[e] + bt[e]);
  *(short8*)out = o;
}

// LN2 over x1 rows (65536 x 512) -> bf16 ; one WAVE per row
__global__ __launch_bounds__(256) void ln2_kernel(
    const float* __restrict__ x1, const float* __restrict__ gamma,
    const float* __restrict__ beta, bf16* __restrict__ out)
{
  long r = (long)blockIdx.x * 4 + (threadIdx.x >> 6);
  int lane = threadIdx.x & 63;
  const float* xr = x1 + r * 512 + lane * 8;
  float v[8];
  *(f32x4*)&v[0] = *(const f32x4*)xr;
  *(f32x4*)&v[4] = *(const f32x4*)(xr + 4);
  float m, rstd;
  wave_stats512(v, m, rstd);
  const float* g = gamma + lane * 8;
  const float* bt = beta + lane * 8;
  short8 o;
  #pragma unroll
  for (int e = 0; e < 8; ++e) o[e] = f2s((v[e] - m) * rstd * g[e] + bt[e]);
  *(short8*)(out + r * 512 + lane * 8) = o;
}

// ---------------- MFMA GEMM, 2-phase double-buffered ----------------
// C = A(MxK) @ Bt(NxK)^T + bias ; LDS linear [128][32] per buffer, staged via
// global_load_lds width-16; stage(t+1) issued BEFORE compute(t); ONE barrier/tile.
// EPI 0: store bf16 (qkv) | 1: gelu->bf16 (mlp hid) | 2: proj residual+unshift
// scatter (f32) | 3: f32 in-place add (mlp out)
template<int EPI>
__global__ __launch_bounds__(256) void gemm_kernel(
    const bf16* __restrict__ A, const bf16* __restrict__ Bt,
    const float* __restrict__ bias, int N, int K,
    bf16* __restrict__ outB, float* __restrict__ outF,
    const float* __restrict__ xin, int rowOffset)
{
  __shared__ bf16 lA0[128 * 32], lB0[128 * 32];
  __shared__ bf16 lA1[128 * 32], lB1[128 * 32];
  const int tid = threadIdx.x;
  const int lane = tid & 63, wave = tid >> 6;
  const int wm = wave >> 1, wn = wave & 1;
  const long row0 = (long)blockIdx.y * 128;
  const int col0 = blockIdx.x * 128;
  f32x4 acc[4][4] = {};
  const int fr = lane & 15, fk = (lane >> 4) * 8;

  // staging geometry
  const int lrow = lane >> 2;          // sub-row within 16-row group
  const int koff = (lane & 3) * 8;     // k-element offset (8 elems = 16B)
  const bf16* gA = A + (row0 + lrow) * (long)K + koff;
  const bf16* gB = Bt + ((long)col0 + lrow) * K + koff;
  const int rb0 = wave * 16;           // q=0 row block
  const int rb1 = 64 + wave * 16;      // q=1 row block
  const long sA0 = (long)rb0 * K, sA1 = (long)rb1 * K;

  auto stage = [&](bf16* dA, bf16* dB, int kt) {
    async_lds16(gA + sA0 + kt, dA + rb0 * 32);
    async_lds16(gA + sA1 + kt, dA + rb1 * 32);
    async_lds16(gB + sA0 + kt, dB + rb0 * 32);
    async_lds16(gB + sA1 + kt, dB + rb1 * 32);
  };
  auto compute = [&](const bf16* cA, const bf16* cB) {
    short8 af[4], bfr[4];
    #pragma unroll
    for (int mi = 0; mi < 4; ++mi) af[mi]  = *(const short8*)&cA[(wm * 64 + mi * 16 + fr) * 32 + fk];
    #pragma unroll
    for (int ni = 0; ni < 4; ++ni) bfr[ni] = *(const short8*)&cB[(wn * 64 + ni * 16 + fr) * 32 + fk];
    #pragma unroll
    for (int mi = 0; mi < 4; ++mi)
      #pragma unroll
      for (int ni = 0; ni < 4; ++ni)
        acc[mi][ni] = __builtin_amdgcn_mfma_f32_16x16x32_bf16(af[mi], bfr[ni], acc[mi][ni], 0, 0, 0);
  };

  const int nt = K >> 5;               // K/32, always even here (16 or 64)
  stage(lA0, lB0, 0);
  __syncthreads();
  for (int t = 0; t < nt; t += 2) {
    stage(lA1, lB1, (t + 1) << 5);     // issue next-tile loads BEFORE compute
    compute(lA0, lB0);
    __syncthreads();                   // drains vmcnt -> lA1/lB1 ready
    if (t + 2 < nt) stage(lA0, lB0, (t + 2) << 5);
    compute(lA1, lB1);
    __syncthreads();
  }

  // epilogue
  const int fg = lane >> 4;
  float bs[4];
  #pragma unroll
  for (int ni = 0; ni < 4; ++ni) bs[ni] = bias[col0 + wn * 64 + ni * 16 + fr];
  #pragma unroll
  for (int mi = 0; mi < 4; ++mi) {
    #pragma unroll
    for (int j = 0; j < 4; ++j) {
      long rr = row0 + wm * 64 + mi * 16 + fg * 4 + j;     // local row
      if (EPI == 2) {
        int grow = rowOffset + (int)rr;                    // global row in [0,66560)
        int ii = grow % NTOK;
        if (ii == 64) continue;                            // drop time token
        int wb = grow / NTOK;
        int b = wb >> 6, w = wb & 63;
        int wh = w >> 3, ww = w & 7, ih = ii >> 3, iw = ii & 7;
        int hh   = ((wh * 8 + ih) + 4) & 63;               // roll(+4) reverse
        int wcol = ((ww * 8 + iw) + 4) & 63;
        long orow = ((long)b * 4096 + hh * 64 + wcol) * 512;
        #pragma unroll
        for (int ni = 0; ni < 4; ++ni) {
          int cc = col0 + wn * 64 + ni * 16 + fr;
          long o = orow + cc;
          outF[o] = xin[o] + acc[mi][ni][j] + bs[ni];      // x1 = shortcut + proj
        }
      } else {
        #pragma unroll
        for (int ni = 0; ni < 4; ++ni) {
          int cc = col0 + wn * 64 + ni * 16 + fr;
          float v = acc[mi][ni][j] + bs[ni];
          if (EPI == 0) {
            outB[rr * N + cc] = __float2bfloat16(v);
          } else if (EPI == 1) {
            float g = 0.5f * v * (1.0f + erff(v * 0.70710678118654752f));
            outB[rr * N + cc] = __float2bfloat16(g);
          } else {                                         // EPI 3
            long o = rr * N + cc;
            outF[o] = outF[o] + v;                         // out = x1 + mlp
          }
        }
      }
    }
  }
}

// ---------------- windowed attention (per window-batch, per head) ----------------
// 4 threads per row: thread (i = tid>>2, s = tid&3). Q in registers, K/V f32 in
// LDS with pad-36 rows (16B aligned, conflict-free float4 reads).
__global__ __launch_bounds__(256) void attn_kernel(
    const bf16* __restrict__ qkv, bf16* __restrict__ attnO,
    const float* __restrict__ btab, int wb0)
{
  __shared__ float lk[65][36], lv[65][36];
  __shared__ float lS[65][66];
  const int lwb = blockIdx.x, h = blockIdx.y, tid = threadIdx.x;
  const int w = (wb0 + lwb) & 63;
  const float scale = 0.17677669529663687f; // 1/sqrt(32)
  const bf16* base = qkv + (long)lwb * 65 * 1536 + h * 32;

  // stage K, V (bf16 -> f32)
  for (int idx = tid; idx < 65 * 4; idx += 256) {
    int i = idx >> 2, c = (idx & 3) * 8;
    short8 kk = *(const short8*)(base + (long)i * 1536 + 512 + c);
    short8 vv = *(const short8*)(base + (long)i * 1536 + 1024 + c);
    #pragma unroll
    for (int e = 0; e < 8; ++e) {
      lk[i][c + e] = b2f(kk[e]);
      lv[i][c + e] = b2f(vv[e]);
    }
  }
  const int iq = tid >> 2, s4 = tid & 3;
  float qreg[32];
  {
    const bf16* qp = base + (long)iq * 1536;
    #pragma unroll
    for (int c = 0; c < 4; ++c) {
      short8 qq = *(const short8*)(qp + c * 8);
      #pragma unroll
      for (int e = 0; e < 8; ++e) qreg[c * 8 + e] = scale * b2f(qq[e]);
    }
  }
  __syncthreads();

  // QK^T + bias + mask
  const int wh = w >> 3, ww = w & 7;
  const int ih = iq >> 3, iwq = iq & 7;
  const int miq = 3 * regidx(wh * 8 + ih) + regidx(ww * 8 + iwq);
  for (int j = s4; j < 65; j += 4) {
    const float* kr = lk[j];
    float s = 0.0f;
    #pragma unroll
    for (int d = 0; d < 32; d += 4) {
      f32x4 kv4 = *(const f32x4*)&kr[d];
      s += qreg[d] * kv4[0] + qreg[d + 1] * kv4[1] + qreg[d + 2] * kv4[2] + qreg[d + 3] * kv4[3];
    }
    if (j < 64) {
      int jh = j >> 3, jw = j & 7;
      s += btab[((ih - jh + 7) * 15 + (iwq - jw + 7)) * HEADS_ + h];
      int mj_ = 3 * regidx(wh * 8 + jh) + regidx(ww * 8 + jw);
      if (miq != mj_) s -= 100.0f;
    }
    lS[iq][j] = s;
  }
  // row 64 (time token): threads 0..3, no bias/mask
  if (tid < 4) {
    float q64[32];
    const bf16* qp = base + (long)64 * 1536;
    #pragma unroll
    for (int c = 0; c < 4; ++c) {
      short8 qq = *(const short8*)(qp + c * 8);
      #pragma unroll
      for (int e = 0; e < 8; ++e) q64[c * 8 + e] = scale * b2f(qq[e]);
    }
    for (int j = tid; j < 65; j += 4) {
      const float* kr = lk[j];
      float s = 0.0f;
      #pragma unroll
      for (int d = 0; d < 32; d += 4) {
        f32x4 kv4 = *(const f32x4*)&kr[d];
        s += q64[d] * kv4[0] + q64[d + 1] * kv4[1] + q64[d + 2] * kv4[2] + q64[d + 3] * kv4[3];
      }
      lS[64][j] = s;
    }
  }
  __syncthreads();

  // softmax, 4 threads per row
  {
    float mx = -1e30f;
    for (int j = s4; j < 65; j += 4) mx = fmaxf(mx, lS[iq][j]);
    mx = fmaxf(mx, __shfl_xor(mx, 1));
    mx = fmaxf(mx, __shfl_xor(mx, 2));
    float sum = 0.0f;
    for (int j = s4; j < 65; j += 4) { float e = __expf(lS[iq][j] - mx); lS[iq][j] = e; sum += e; }
    sum += __shfl_xor(sum, 1);
    sum += __shfl_xor(sum, 2);
    float inv = 1.0f / sum;
    for (int j = s4; j < 65; j += 4) lS[iq][j] *= inv;
  }
  if (tid < 4) {
    float mx = -1e30f;
    for (int j = tid; j < 65; j += 4) mx = fmaxf(mx, lS[64][j]);
    mx = fmaxf(mx, __shfl_xor(mx, 1));
    mx = fmaxf(mx, __shfl_xor(mx, 2));
    float sum = 0.0f;
    for (int j = tid; j < 65; j += 4) { float e = __expf(lS[64][j] - mx); lS[64][j] = e; sum += e; }
    sum += __shfl_xor(sum, 1);
    sum += __shfl_xor(sum, 2);
    float inv = 1.0f / sum;
    for (int j = tid; j < 65; j += 4) lS[64][j] *= inv;
  }
  __syncthreads();

  // PV: thread (iq, s4) computes out[iq][s4*8 .. s4*8+7]
  const int d0 = s4 * 8;
  {
    f32x4 o0 = {0, 0, 0, 0}, o1 = {0, 0, 0, 0};
    for (int j = 0; j < 65; ++j) {
      float p = lS[iq][j];
      o0 += p * *(const f32x4*)&lv[j][d0];
      o1 += p * *(const f32x4*)&lv[j][d0 + 4];
    }
    short8 os;
    #pragma unroll
    for (int e = 0; e < 4; ++e) { os[e] = f2s(o0[e]); os[4 + e] = f2s(o1[e]); }
    *(short8*)(attnO + (long)(lwb * 65 + iq) * 512 + h * 32 + d0) = os;
  }
  if (tid < 4) {
    int dd = tid * 8;
    f32x4 o0 = {0, 0, 0, 0}, o1 = {0, 0, 0, 0};
    for (int j = 0; j < 65; ++j) {
      float p = lS[64][j];
      o0 += p * *(const f32x4*)&lv[j][dd];
      o1 += p * *(const f32x4*)&lv[j][dd + 4];
    }
    short8 os;
    #pragma unroll
    for (int e = 0; e < 4; ++e) { os[e] = f2s(o0[e]); os[4 + e] = f2s(o1[e]); }
    *(short8*)(attnO + (long)(lwb * 65 + 64) * 512 + h * 32 + dd) = os;
  }
}

// ---------------- host ----------------

extern "C" void kernel_launch(void* const* d_in, const int* in_sizes, int n_in,
                              void* d_out, int out_size, void* d_ws, size_t ws_size,
                              hipStream_t stream)
{
  const float* x      = (const float*)d_in[0];
  const float* emb    = (const float*)d_in[1];
  const float* gamma1 = (const float*)d_in[2];
  const float* beta1  = (const float*)d_in[3];
  const float* W_emb  = (const float*)d_in[4];
  const float* b_emb  = (const float*)d_in[5];
  const float* W_qkv  = (const float*)d_in[6];
  const float* b_qkv  = (const float*)d_in[7];
  const float* btab   = (const float*)d_in[8];
  const float* W_proj = (const float*)d_in[9];
  const float* b_proj = (const float*)d_in[10];
  const float* gamma2 = (const float*)d_in[11];
  const float* beta2  = (const float*)d_in[12];
  const float* W1     = (const float*)d_in[13];
  const float* b1     = (const float*)d_in[14];
  const float* W2     = (const float*)d_in[15];
  const float* b2     = (const float*)d_in[16];
  float* out = (float*)d_out;

  char* ws = (char*)d_ws;
  size_t off = 0;
  auto alloc = [&](size_t bytes) -> char* {
    char* p = ws + off;
    off += (bytes + 255) & ~(size_t)255;
    return p;
  };
  bf16* wt_qkv  = (bf16*)alloc((size_t)1536 * 512 * 2);
  bf16* wt_proj = (bf16*)alloc((size_t)512 * 512 * 2);
  bf16* wt1     = (bf16*)alloc((size_t)2048 * 512 * 2);
  bf16* wt2     = (bf16*)alloc((size_t)512 * 2048 * 2);
  float* tvec   = (float*)alloc((size_t)16 * 512 * 4);
  // region A: xw (66560x512 bf16) ... later reused as ln2b (65536x512 bf16)
  char* regionA = alloc((size_t)TOTROWS * 512 * 2);
  bf16* xw   = (bf16*)regionA;
  bf16* ln2b = (bf16*)regionA;
  bf16* qkv_c = (bf16*)alloc((size_t)ATT_CHUNK_ROWS * 1536 * 2);
  // region B: attnO (66560x512 bf16) ... later reused as h_c (16384x2048 bf16)
  char* regionB = alloc((size_t)TOTROWS * 512 * 2);
  bf16* attnO = (bf16*)regionB;
  bf16* h_c   = (bf16*)regionB;
  (void)ws_size; (void)n_in; (void)in_sizes; (void)out_size;

  // weight prep
  transpose_cast_kernel<<<dim3(1536 / 32, 512 / 32), dim3(32, 8), 0, stream>>>(W_qkv, wt_qkv, 512, 1536);
  transpose_cast_kernel<<<dim3(512 / 32, 512 / 32),  dim3(32, 8), 0, stream>>>(W_proj, wt_proj, 512, 512);
  transpose_cast_kernel<<<dim3(2048 / 32, 512 / 32), dim3(32, 8), 0, stream>>>(W1, wt1, 512, 2048);
  transpose_cast_kernel<<<dim3(512 / 32, 2048 / 32), dim3(32, 8), 0, stream>>>(W2, wt2, 2048, 512);
  time_emb_kernel<<<dim3(16, 2), 256, 0, stream>>>(emb, W_emb, b_emb, tvec);

  // LN1 + shift + window partition + time token (wave per row)
  ln1_window_kernel<<<TOTROWS / 4, 256, 0, stream>>>(x, gamma1, beta1, tvec, xw);

  // attention path: qkv + attn chunked, attnO accumulated full
  for (int ac = 0; ac < 8; ++ac) {
    long r0 = (long)ac * ATT_CHUNK_ROWS;
    gemm_kernel<0><<<dim3(1536 / 128, ATT_CHUNK_ROWS / 128), 256, 0, stream>>>(
        xw + r0 * 512, wt_qkv, b_qkv, 1536, 512, qkv_c, nullptr, nullptr, 0);
    attn_kernel<<<dim3(ATT_CHUNK_WB, HEADS_), 256, 0, stream>>>(
        qkv_c, attnO + r0 * 512, btab, ac * ATT_CHUNK_WB);
  }
  // proj: single dispatch over all rows (residual + window-reverse fused)
  gemm_kernel<2><<<dim3(512 / 128, TOTROWS / 128), 256, 0, stream>>>(
      attnO, wt_proj, b_proj, 512, 512, nullptr, out, x, 0);

  // LN2 (reuses region A; xw is dead)
  ln2_kernel<<<65536 / 4, 256, 0, stream>>>(out, gamma2, beta2, ln2b);

  // MLP, 4 chunks of 16384 rows (h_c reuses region B; attnO is dead)
  for (int mc = 0; mc < 4; ++mc) {
    long r0 = (long)mc * MLP_CHUNK_ROWS;
    gemm_kernel<1><<<dim3(2048 / 128, MLP_CHUNK_ROWS / 128), 256, 0, stream>>>(
        ln2b + r0 * 512, wt1, b1, 2048, 512, h_c, nullptr, nullptr, 0);
    gemm_kernel<3><<<dim3(512 / 128, MLP_CHUNK_ROWS / 128), 256, 0, stream>>>(
        h_c, wt2, b2, 512, 2048, nullptr, out + r0 * 512, nullptr, 0);
  }
}

// Round 4
// 1180.605 us; speedup vs baseline: 2.1412x; 1.1505x over previous
//
#include <hip/hip_runtime.h>
#include <hip/hip_bf16.h>

typedef __hip_bfloat16 bf16;
typedef short short8 __attribute__((ext_vector_type(8)));
typedef float f32x4 __attribute__((ext_vector_type(4)));

// static config
#define DIMC 512
#define HEADS_ 16
#define NTOK 65        // 64 window tokens + 1 time token
#define NWIN 64
#define NB 16
#define HID 2048
#define TOTROWS 66560  // 16*64*65
#define ATT_CHUNK_WB 128                      // window-batches per attention chunk
#define ATT_CHUNK_ROWS (ATT_CHUNK_WB * NTOK)  // 8320
#define MLP_CHUNK_ROWS 16384

// ---------------- helpers ----------------

__device__ __forceinline__ int regidx(int p) { return p < 56 ? 0 : (p < 60 ? 1 : 2); }

__device__ __forceinline__ float b2f(short s) {
  unsigned int u = ((unsigned int)(unsigned short)s) << 16;
  float f; __builtin_memcpy(&f, &u, 4); return f;
}
__device__ __forceinline__ short f2s(float f) {
  bf16 b = __float2bfloat16(f);
  short s; __builtin_memcpy(&s, &b, 2); return s;
}

// async global->LDS, 16B per lane; LDS dest is wave-uniform base + lane*16
__device__ __forceinline__ void async_lds16(const bf16* g, bf16* l) {
  __builtin_amdgcn_global_load_lds(
      (const __attribute__((address_space(1))) unsigned int*)g,
      (__attribute__((address_space(3))) unsigned int*)l,
      16, 0, 0);
}

// per-wave LN stats over 512 elems (8 per lane)
__device__ __forceinline__ void wave_stats512(const float* v, float& m, float& rstd)
{
  float s = 0.0f, ss = 0.0f;
  #pragma unroll
  for (int e = 0; e < 8; ++e) { s += v[e]; ss += v[e] * v[e]; }
  #pragma unroll
  for (int o = 1; o < 64; o <<= 1) { s += __shfl_xor(s, o); ss += __shfl_xor(ss, o); }
  m = s * (1.0f / 512.0f);
  rstd = rsqrtf(ss * (1.0f / 512.0f) - m * m + 1e-5f);
}

// ---------------- small kernels ----------------

__global__ __launch_bounds__(256) void time_emb_kernel(
    const float* __restrict__ emb, const float* __restrict__ W_emb,
    const float* __restrict__ b_emb, float* __restrict__ t)
{
  int b = blockIdx.x;
  int c = blockIdx.y * 256 + threadIdx.x;
  __shared__ float se[512];
  for (int k = threadIdx.x; k < 512; k += 256) {
    float e = emb[b * 512 + k];
    se[k] = e / (1.0f + expf(-e));
  }
  __syncthreads();
  float acc = b_emb[c];
  for (int k = 0; k < 512; ++k) acc += se[k] * W_emb[k * 512 + c];
  t[b * 512 + c] = acc;
}

// W (Kd x Nd) f32 -> Wt (Nd x Kd) bf16
__global__ void transpose_cast_kernel(const float* __restrict__ W, bf16* __restrict__ Wt,
                                      int Kd, int Nd)
{
  __shared__ float tile[32][33];
  int n0 = blockIdx.x * 32, k0 = blockIdx.y * 32;
  for (int r = threadIdx.y; r < 32; r += 8)
    tile[r][threadIdx.x] = W[(long)(k0 + r) * Nd + n0 + threadIdx.x];
  __syncthreads();
  for (int r = threadIdx.y; r < 32; r += 8)
    Wt[(long)(n0 + r) * Kd + k0 + threadIdx.x] = __float2bfloat16(tile[threadIdx.x][r]);
}

// LN1 + cyclic shift + window partition + time-token append -> xw bf16 (66560 x 512)
__global__ __launch_bounds__(256) void ln1_window_kernel(
    const float* __restrict__ x, const float* __restrict__ gamma,
    const float* __restrict__ beta, const float* __restrict__ t,
    bf16* __restrict__ xw)
{
  long r = (long)blockIdx.x * 4 + (threadIdx.x >> 6);   // 0..66559
  int lane = threadIdx.x & 63;
  int wb = (int)(r / NTOK), i = (int)(r % NTOK);
  int b = wb >> 6, w = wb & 63;
  bf16* out = xw + r * 512 + lane * 8;
  if (i == 64) {
    const float* tr = t + b * 512 + lane * 8;
    short8 o;
    #pragma unroll
    for (int e = 0; e < 8; ++e) o[e] = f2s(tr[e]);
    *(short8*)out = o;
    return;
  }
  int wh = w >> 3, ww = w & 7, ih = i >> 3, iw = i & 7;
  int hsrc = ((wh * 8 + ih) + 4) & 63;
  int wsrc = ((ww * 8 + iw) + 4) & 63;
  const float* xr = x + ((long)b * 4096 + hsrc * 64 + wsrc) * 512 + lane * 8;
  float v[8];
  *(f32x4*)&v[0] = *(const f32x4*)xr;
  *(f32x4*)&v[4] = *(const f32x4*)(xr + 4);
  float m, rstd;
  wave_stats512(v, m, rstd);
  const float* g = gamma + lane * 8;
  const float* bt = beta + lane * 8;
  short8 o;
  #pragma unroll
  for (int e = 0; e < 8; ++e) o[e] = f2s((v[e] - m) * rstd * g[e] + bt[e]);
  *(short8*)out = o;
}

// LN2 over x1 rows (65536 x 512) -> bf16 ; one WAVE per row
__global__ __launch_bounds__(256) void ln2_kernel(
    const float* __restrict__ x1, const float* __restrict__ gamma,
    const float* __restrict__ beta, bf16* __restrict__ out)
{
  long r = (long)blockIdx.x * 4 + (threadIdx.x >> 6);
  int lane = threadIdx.x & 63;
  const float* xr = x1 + r * 512 + lane * 8;
  float v[8];
  *(f32x4*)&v[0] = *(const f32x4*)xr;
  *(f32x4*)&v[4] = *(const f32x4*)(xr + 4);
  float m, rstd;
  wave_stats512(v, m, rstd);
  const float* g = gamma + lane * 8;
  const float* bt = beta + lane * 8;
  short8 o;
  #pragma unroll
  for (int e = 0; e < 8; ++e) o[e] = f2s((v[e] - m) * rstd * g[e] + bt[e]);
  *(short8*)(out + r * 512 + lane * 8) = o;
}

// ---------------- 256x256 8-wave MFMA GEMM, raw-barrier pipelined ----------------
// C = A(MxK) @ Bt(NxK)^T + bias. 512 threads, waves 2(M)x4(N), per-wave 128x64.
// LDS 128 KiB: lds[buf][A/B][256*64] bf16, XOR-swizzled 16B slots (slot ^= row&7),
// staged via global_load_lds w=16 with pre-swizzled per-lane global source.
// Per K-tile (BK=64): 4 phases {ds_read 2 A-rows-of-frags | phase0: +B frags +
// stage next tile -> raw s_barrier -> setprio 16 MFMA -> barrier}; vmcnt(0)
// once per K-tile (before last barrier). EPI as before.
template<int EPI>
__global__ __launch_bounds__(512, 2) void gemm8_kernel(
    const bf16* __restrict__ A, const bf16* __restrict__ Bt,
    const float* __restrict__ bias, int N, int K,
    bf16* __restrict__ outB, float* __restrict__ outF,
    const float* __restrict__ xin, int rowOffset)
{
  __shared__ bf16 lds[2][2][256 * 64];
  const int tid = threadIdx.x;
  const int lane = tid & 63;
  const int wv = tid >> 6;             // 0..7
  const int wm = wv >> 2, wn = wv & 3; // 2 x 4
  const int fr = lane & 15, fg = lane >> 4;
  const long row0 = (long)blockIdx.y * 256;
  const long col0 = (long)blockIdx.x * 256;

  // staging geometry: wave covers chunks {2wv, 2wv+1} (8 rows each) in each half
  const int srow = lane >> 3;                 // 0..7
  const int sslot = (lane & 7) ^ srow;        // pre-swizzled global 16B slot
  const int c0 = wv * 2;

  f32x4 acc[8][4] = {};
  const int nkt = K >> 6;

  auto stage_tile = [&](int buf, int gk) {
    #pragma unroll
    for (int q2 = 0; q2 < 2; ++q2) {
      int rr = (c0 + q2) * 8;                 // rows rr..rr+7 (half 0), +128 (half 1)
      const bf16* pA = A + (row0 + rr + srow) * (long)K + gk + sslot * 8;
      const bf16* pB = Bt + (col0 + rr + srow) * (long)K + gk + sslot * 8;
      bf16* dA = &lds[buf][0][rr * 64];
      bf16* dB = &lds[buf][1][rr * 64];
      async_lds16(pA, dA);
      async_lds16(pA + (long)128 * K, dA + 128 * 64);
      async_lds16(pB, dB);
      async_lds16(pB + (long)128 * K, dB + 128 * 64);
    }
  };
  auto frag = [&](const bf16* tile, int row, int slotB) -> short8 {
    return *(const short8*)((const char*)tile + row * 128 + ((slotB ^ (row & 7)) << 4));
  };

  stage_tile(0, 0);
  asm volatile("s_waitcnt vmcnt(0)" ::: "memory");
  asm volatile("s_barrier" ::: "memory");

  for (int i = 0; i < nkt; ++i) {
    const bf16* At = &lds[i & 1][0][0];
    const bf16* Bl = &lds[i & 1][1][0];
    const bool st = (i + 1 < nkt);
    short8 breg[4][2];
    #pragma unroll
    for (int ph = 0; ph < 4; ++ph) {
      short8 a[2][2];
      #pragma unroll
      for (int m2 = 0; m2 < 2; ++m2)
        #pragma unroll
        for (int ks = 0; ks < 2; ++ks)
          a[m2][ks] = frag(At, wm * 128 + (ph * 2 + m2) * 16 + fr, ks * 4 + fg);
      if (ph == 0) {
        #pragma unroll
        for (int ni = 0; ni < 4; ++ni)
          #pragma unroll
          for (int ks = 0; ks < 2; ++ks)
            breg[ni][ks] = frag(Bl, wn * 64 + ni * 16 + fr, ks * 4 + fg);
        if (st) stage_tile((i & 1) ^ 1, (i + 1) << 6);
      }
      asm volatile("s_barrier" ::: "memory");
      __builtin_amdgcn_s_setprio(1);
      #pragma unroll
      for (int m2 = 0; m2 < 2; ++m2)
        #pragma unroll
        for (int ni = 0; ni < 4; ++ni)
          #pragma unroll
          for (int ks = 0; ks < 2; ++ks)
            acc[ph * 2 + m2][ni] = __builtin_amdgcn_mfma_f32_16x16x32_bf16(
                a[m2][ks], breg[ni][ks], acc[ph * 2 + m2][ni], 0, 0, 0);
      __builtin_amdgcn_s_setprio(0);
      if (ph == 3 && st) asm volatile("s_waitcnt vmcnt(0)" ::: "memory");
      asm volatile("s_barrier" ::: "memory");
    }
  }

  // epilogue
  float bs[4];
  #pragma unroll
  for (int ni = 0; ni < 4; ++ni) bs[ni] = bias[col0 + wn * 64 + ni * 16 + fr];
  #pragma unroll
  for (int mi = 0; mi < 8; ++mi) {
    #pragma unroll
    for (int j = 0; j < 4; ++j) {
      long rr = row0 + wm * 128 + mi * 16 + fg * 4 + j;    // local row
      if (EPI == 2) {
        int grow = rowOffset + (int)rr;                    // global row in [0,66560)
        int ii = grow % NTOK;
        if (ii == 64) continue;                            // drop time token
        int wb = grow / NTOK;
        int b = wb >> 6, w = wb & 63;
        int wh = w >> 3, ww = w & 7, ih = ii >> 3, iw = ii & 7;
        int hh   = ((wh * 8 + ih) + 4) & 63;               // roll(+4) reverse
        int wcol = ((ww * 8 + iw) + 4) & 63;
        long orow = ((long)b * 4096 + hh * 64 + wcol) * 512;
        #pragma unroll
        for (int ni = 0; ni < 4; ++ni) {
          long o = orow + col0 + wn * 64 + ni * 16 + fr;
          outF[o] = xin[o] + acc[mi][ni][j] + bs[ni];      // x1 = shortcut + proj
        }
      } else {
        #pragma unroll
        for (int ni = 0; ni < 4; ++ni) {
          long cc = col0 + wn * 64 + ni * 16 + fr;
          float v = acc[mi][ni][j] + bs[ni];
          if (EPI == 0) {
            outB[rr * N + cc] = __float2bfloat16(v);
          } else if (EPI == 1) {
            float g = 0.5f * v * (1.0f + erff(v * 0.70710678118654752f));
            outB[rr * N + cc] = __float2bfloat16(g);
          } else {                                         // EPI 3
            long o = rr * N + cc;
            outF[o] = outF[o] + v;                         // out = x1 + mlp
          }
        }
      }
    }
  }
}

// ---------------- windowed attention (per window-batch, per head) ----------------
__global__ __launch_bounds__(256) void attn_kernel(
    const bf16* __restrict__ qkv, bf16* __restrict__ attnO,
    const float* __restrict__ btab, int wb0)
{
  __shared__ float lk[65][36], lv[65][36];
  __shared__ float lS[65][66];
  const int lwb = blockIdx.x, h = blockIdx.y, tid = threadIdx.x;
  const int w = (wb0 + lwb) & 63;
  const float scale = 0.17677669529663687f; // 1/sqrt(32)
  const bf16* base = qkv + (long)lwb * 65 * 1536 + h * 32;

  for (int idx = tid; idx < 65 * 4; idx += 256) {
    int i = idx >> 2, c = (idx & 3) * 8;
    short8 kk = *(const short8*)(base + (long)i * 1536 + 512 + c);
    short8 vv = *(const short8*)(base + (long)i * 1536 + 1024 + c);
    #pragma unroll
    for (int e = 0; e < 8; ++e) {
      lk[i][c + e] = b2f(kk[e]);
      lv[i][c + e] = b2f(vv[e]);
    }
  }
  const int iq = tid >> 2, s4 = tid & 3;
  float qreg[32];
  {
    const bf16* qp = base + (long)iq * 1536;
    #pragma unroll
    for (int c = 0; c < 4; ++c) {
      short8 qq = *(const short8*)(qp + c * 8);
      #pragma unroll
      for (int e = 0; e < 8; ++e) qreg[c * 8 + e] = scale * b2f(qq[e]);
    }
  }
  __syncthreads();

  const int wh = w >> 3, ww = w & 7;
  const int ih = iq >> 3, iwq = iq & 7;
  const int miq = 3 * regidx(wh * 8 + ih) + regidx(ww * 8 + iwq);
  for (int j = s4; j < 65; j += 4) {
    const float* kr = lk[j];
    float s = 0.0f;
    #pragma unroll
    for (int d = 0; d < 32; d += 4) {
      f32x4 kv4 = *(const f32x4*)&kr[d];
      s += qreg[d] * kv4[0] + qreg[d + 1] * kv4[1] + qreg[d + 2] * kv4[2] + qreg[d + 3] * kv4[3];
    }
    if (j < 64) {
      int jh = j >> 3, jw = j & 7;
      s += btab[((ih - jh + 7) * 15 + (iwq - jw + 7)) * HEADS_ + h];
      int mj_ = 3 * regidx(wh * 8 + jh) + regidx(ww * 8 + jw);
      if (miq != mj_) s -= 100.0f;
    }
    lS[iq][j] = s;
  }
  if (tid < 4) {
    float q64[32];
    const bf16* qp = base + (long)64 * 1536;
    #pragma unroll
    for (int c = 0; c < 4; ++c) {
      short8 qq = *(const short8*)(qp + c * 8);
      #pragma unroll
      for (int e = 0; e < 8; ++e) q64[c * 8 + e] = scale * b2f(qq[e]);
    }
    for (int j = tid; j < 65; j += 4) {
      const float* kr = lk[j];
      float s = 0.0f;
      #pragma unroll
      for (int d = 0; d < 32; d += 4) {
        f32x4 kv4 = *(const f32x4*)&kr[d];
        s += q64[d] * kv4[0] + q64[d + 1] * kv4[1] + q64[d + 2] * kv4[2] + q64[d + 3] * kv4[3];
      }
      lS[64][j] = s;
    }
  }
  __syncthreads();

  {
    float mx = -1e30f;
    for (int j = s4; j < 65; j += 4) mx = fmaxf(mx, lS[iq][j]);
    mx = fmaxf(mx, __shfl_xor(mx, 1));
    mx = fmaxf(mx, __shfl_xor(mx, 2));
    float sum = 0.0f;
    for (int j = s4; j < 65; j += 4) { float e = __expf(lS[iq][j] - mx); lS[iq][j] = e; sum += e; }
    sum += __shfl_xor(sum, 1);
    sum += __shfl_xor(sum, 2);
    float inv = 1.0f / sum;
    for (int j = s4; j < 65; j += 4) lS[iq][j] *= inv;
  }
  if (tid < 4) {
    float mx = -1e30f;
    for (int j = tid; j < 65; j += 4) mx = fmaxf(mx, lS[64][j]);
    mx = fmaxf(mx, __shfl_xor(mx, 1));
    mx = fmaxf(mx, __shfl_xor(mx, 2));
    float sum = 0.0f;
    for (int j = tid; j < 65; j += 4) { float e = __expf(lS[64][j] - mx); lS[64][j] = e; sum += e; }
    sum += __shfl_xor(sum, 1);
    sum += __shfl_xor(sum, 2);
    float inv = 1.0f / sum;
    for (int j = tid; j < 65; j += 4) lS[64][j] *= inv;
  }
  __syncthreads();

  const int d0 = s4 * 8;
  {
    f32x4 o0 = {0, 0, 0, 0}, o1 = {0, 0, 0, 0};
    for (int j = 0; j < 65; ++j) {
      float p = lS[iq][j];
      o0 += p * *(const f32x4*)&lv[j][d0];
      o1 += p * *(const f32x4*)&lv[j][d0 + 4];
    }
    short8 os;
    #pragma unroll
    for (int e = 0; e < 4; ++e) { os[e] = f2s(o0[e]); os[4 + e] = f2s(o1[e]); }
    *(short8*)(attnO + (long)(lwb * 65 + iq) * 512 + h * 32 + d0) = os;
  }
  if (tid < 4) {
    int dd = tid * 8;
    f32x4 o0 = {0, 0, 0, 0}, o1 = {0, 0, 0, 0};
    for (int j = 0; j < 65; ++j) {
      float p = lS[64][j];
      o0 += p * *(const f32x4*)&lv[j][dd];
      o1 += p * *(const f32x4*)&lv[j][dd + 4];
    }
    short8 os;
    #pragma unroll
    for (int e = 0; e < 4; ++e) { os[e] = f2s(o0[e]); os[4 + e] = f2s(o1[e]); }
    *(short8*)(attnO + (long)(lwb * 65 + 64) * 512 + h * 32 + dd) = os;
  }
}

// ---------------- host ----------------

extern "C" void kernel_launch(void* const* d_in, const int* in_sizes, int n_in,
                              void* d_out, int out_size, void* d_ws, size_t ws_size,
                              hipStream_t stream)
{
  const float* x      = (const float*)d_in[0];
  const float* emb    = (const float*)d_in[1];
  const float* gamma1 = (const float*)d_in[2];
  const float* beta1  = (const float*)d_in[3];
  const float* W_emb  = (const float*)d_in[4];
  const float* b_emb  = (const float*)d_in[5];
  const float* W_qkv  = (const float*)d_in[6];
  const float* b_qkv  = (const float*)d_in[7];
  const float* btab   = (const float*)d_in[8];
  const float* W_proj = (const float*)d_in[9];
  const float* b_proj = (const float*)d_in[10];
  const float* gamma2 = (const float*)d_in[11];
  const float* beta2  = (const float*)d_in[12];
  const float* W1     = (const float*)d_in[13];
  const float* b1     = (const float*)d_in[14];
  const float* W2     = (const float*)d_in[15];
  const float* b2     = (const float*)d_in[16];
  float* out = (float*)d_out;
  (void)n_in; (void)in_sizes; (void)out_size;

  char* ws = (char*)d_ws;
  size_t off = 0;
  auto alloc = [&](size_t bytes) -> char* {
    char* p = ws + off;
    off += (bytes + 255) & ~(size_t)255;
    return p;
  };
  bf16* wt_qkv  = (bf16*)alloc((size_t)1536 * 512 * 2);
  bf16* wt_proj = (bf16*)alloc((size_t)512 * 512 * 2);
  bf16* wt1     = (bf16*)alloc((size_t)2048 * 512 * 2);
  bf16* wt2     = (bf16*)alloc((size_t)512 * 2048 * 2);
  float* tvec   = (float*)alloc((size_t)16 * 512 * 4);

  // big layout needs ~348 MB: [xw | qkv | attnO], h aliases [qkv..attnO], ln2b aliases xw
  const size_t sz_xw    = (size_t)TOTROWS * 512 * 2;
  const size_t sz_qkv   = (size_t)TOTROWS * 1536 * 2;
  const size_t sz_attnO = (size_t)TOTROWS * 512 * 2;
  const bool big = ws_size >= off + sz_xw + sz_qkv + sz_attnO + (4u << 20);

  // weight prep (common)
  transpose_cast_kernel<<<dim3(1536 / 32, 512 / 32), dim3(32, 8), 0, stream>>>(W_qkv, wt_qkv, 512, 1536);
  transpose_cast_kernel<<<dim3(512 / 32, 512 / 32),  dim3(32, 8), 0, stream>>>(W_proj, wt_proj, 512, 512);
  transpose_cast_kernel<<<dim3(2048 / 32, 512 / 32), dim3(32, 8), 0, stream>>>(W1, wt1, 512, 2048);
  transpose_cast_kernel<<<dim3(512 / 32, 2048 / 32), dim3(32, 8), 0, stream>>>(W2, wt2, 2048, 512);
  time_emb_kernel<<<dim3(16, 2), 256, 0, stream>>>(emb, W_emb, b_emb, tvec);

  if (big) {
    bf16* xw    = (bf16*)alloc(sz_xw);
    bf16* qkv   = (bf16*)alloc(sz_qkv);
    bf16* attnO = (bf16*)alloc(sz_attnO);
    bf16* ln2b  = xw;          // xw dead after qkv GEMM
    bf16* h     = qkv;         // qkv+attnO regions dead after proj; 268 MB fits 273

    ln1_window_kernel<<<TOTROWS / 4, 256, 0, stream>>>(x, gamma1, beta1, tvec, xw);
    gemm8_kernel<0><<<dim3(6, 260), 512, 0, stream>>>(
        xw, wt_qkv, b_qkv, 1536, 512, qkv, nullptr, nullptr, 0);
    attn_kernel<<<dim3(NB * NWIN, HEADS_), 256, 0, stream>>>(qkv, attnO, btab, 0);
    gemm8_kernel<2><<<dim3(2, 260), 512, 0, stream>>>(
        attnO, wt_proj, b_proj, 512, 512, nullptr, out, x, 0);
    ln2_kernel<<<65536 / 4, 256, 0, stream>>>(out, gamma2, beta2, ln2b);
    gemm8_kernel<1><<<dim3(8, 256), 512, 0, stream>>>(
        ln2b, wt1, b1, 2048, 512, h, nullptr, nullptr, 0);
    gemm8_kernel<3><<<dim3(2, 256), 512, 0, stream>>>(
        h, wt2, b2, 512, 2048, nullptr, out, nullptr, 0);
  } else {
    // chunked fallback (proven ~168 MB layout)
    char* regionA = alloc(sz_xw);                     // xw, later ln2b
    bf16* xw   = (bf16*)regionA;
    bf16* ln2b = (bf16*)regionA;
    bf16* qkv_c = (bf16*)alloc((size_t)8448 * 1536 * 2);  // padded to 33*256 rows
    char* regionB = alloc(sz_attnO);                  // attnO, later h_c
    bf16* attnO = (bf16*)regionB;
    bf16* h_c   = (bf16*)regionB;

    ln1_window_kernel<<<TOTROWS / 4, 256, 0, stream>>>(x, gamma1, beta1, tvec, xw);
    for (int ac = 0; ac < 8; ++ac) {
      long r0 = (long)ac * ATT_CHUNK_ROWS;
      gemm8_kernel<0><<<dim3(6, 33), 512, 0, stream>>>(
          xw + r0 * 512, wt_qkv, b_qkv, 1536, 512, qkv_c, nullptr, nullptr, 0);
      attn_kernel<<<dim3(ATT_CHUNK_WB, HEADS_), 256, 0, stream>>>(
          qkv_c, attnO + r0 * 512, btab, ac * ATT_CHUNK_WB);
    }
    gemm8_kernel<2><<<dim3(2, 260), 512, 0, stream>>>(
        attnO, wt_proj, b_proj, 512, 512, nullptr, out, x, 0);
    ln2_kernel<<<65536 / 4, 256, 0, stream>>>(out, gamma2, beta2, ln2b);
    for (int mc = 0; mc < 4; ++mc) {
      long r0 = (long)mc * MLP_CHUNK_ROWS;
      gemm8_kernel<1><<<dim3(8, 64), 512, 0, stream>>>(
          ln2b + r0 * 512, wt1, b1, 2048, 512, h_c, nullptr, nullptr, 0);
      gemm8_kernel<3><<<dim3(2, 64), 512, 0, stream>>>(
          h_c, wt2, b2, 512, 2048, nullptr, out + r0 * 512, nullptr, 0);
    }
  }
}

// Round 6
// 943.006 us; speedup vs baseline: 2.6807x; 1.2520x over previous
//
#include <hip/hip_runtime.h>
#include <hip/hip_bf16.h>

typedef __hip_bfloat16 bf16;
typedef short short4_t __attribute__((ext_vector_type(4)));
typedef short short8 __attribute__((ext_vector_type(8)));
typedef float f32x4 __attribute__((ext_vector_type(4)));

// static config
#define DIMC 512
#define HEADS_ 16
#define NTOK 65        // 64 window tokens + 1 time token
#define NWIN 64
#define NB 16
#define HID 2048
#define TOTROWS 66560  // 16*64*65
#define ATT_CHUNK_WB 128                      // window-batches per attention chunk
#define ATT_CHUNK_ROWS (ATT_CHUNK_WB * NTOK)  // 8320
#define MLP_CHUNK_ROWS 16384

// ---------------- helpers ----------------

__device__ __forceinline__ float b2f(short s) {
  unsigned int u = ((unsigned int)(unsigned short)s) << 16;
  float f; __builtin_memcpy(&f, &u, 4); return f;
}
__device__ __forceinline__ short f2s(float f) {
  bf16 b = __float2bfloat16(f);
  short s; __builtin_memcpy(&s, &b, 2); return s;
}

// async global->LDS, 16B per lane; LDS dest is wave-uniform base + lane*16
__device__ __forceinline__ void async_lds16(const bf16* g, bf16* l) {
  __builtin_amdgcn_global_load_lds(
      (const __attribute__((address_space(1))) unsigned int*)g,
      (__attribute__((address_space(3))) unsigned int*)l,
      16, 0, 0);
}

// per-wave LN stats over 512 elems (8 per lane)
__device__ __forceinline__ void wave_stats512(const float* v, float& m, float& rstd)
{
  float s = 0.0f, ss = 0.0f;
  #pragma unroll
  for (int e = 0; e < 8; ++e) { s += v[e]; ss += v[e] * v[e]; }
  #pragma unroll
  for (int o = 1; o < 64; o <<= 1) { s += __shfl_xor(s, o); ss += __shfl_xor(ss, o); }
  m = s * (1.0f / 512.0f);
  rstd = rsqrtf(ss * (1.0f / 512.0f) - m * m + 1e-5f);
}

// ---------------- small kernels ----------------

__global__ __launch_bounds__(256) void time_emb_kernel(
    const float* __restrict__ emb, const float* __restrict__ W_emb,
    const float* __restrict__ b_emb, float* __restrict__ t)
{
  int b = blockIdx.x;
  int c = blockIdx.y * 256 + threadIdx.x;
  __shared__ float se[512];
  for (int k = threadIdx.x; k < 512; k += 256) {
    float e = emb[b * 512 + k];
    se[k] = e / (1.0f + expf(-e));
  }
  __syncthreads();
  float acc = b_emb[c];
  for (int k = 0; k < 512; ++k) acc += se[k] * W_emb[k * 512 + c];
  t[b * 512 + c] = acc;
}

// W (Kd x Nd) f32 -> Wt (Nd x Kd) bf16
__global__ void transpose_cast_kernel(const float* __restrict__ W, bf16* __restrict__ Wt,
                                      int Kd, int Nd)
{
  __shared__ float tile[32][33];
  int n0 = blockIdx.x * 32, k0 = blockIdx.y * 32;
  for (int r = threadIdx.y; r < 32; r += 8)
    tile[r][threadIdx.x] = W[(long)(k0 + r) * Nd + n0 + threadIdx.x];
  __syncthreads();
  for (int r = threadIdx.y; r < 32; r += 8)
    Wt[(long)(n0 + r) * Kd + k0 + threadIdx.x] = __float2bfloat16(tile[threadIdx.x][r]);
}

// combined bias+mask table: tbl[h][wtype][i(query) 80][t(key) 80] f32
// t>=65 -> -1e30 (kills padded keys); t==64 or i>=64 -> 0; else rel-bias + mask.
__global__ __launch_bounds__(256) void bias_mask_kernel(
    const float* __restrict__ btab, float* __restrict__ tbl)
{
  int h = blockIdx.x, wt = blockIdx.y;
  for (int idx = threadIdx.x; idx < 6400; idx += 256) {
    int i = idx / 80, t = idx % 80;
    float v;
    if (t >= 65) v = -1e30f;
    else if (i >= 64 || t == 64) v = 0.0f;
    else {
      int rel = (((i >> 3) - (t >> 3) + 7) * 15) + ((i & 7) - (t & 7) + 7);
      v = btab[rel * HEADS_ + h];
      int rci = (wt & 2) ? (((i >> 3) < 4) ? 1 : 2) : 0;
      int cci = (wt & 1) ? (((i & 7) < 4) ? 1 : 2) : 0;
      int rct = (wt & 2) ? (((t >> 3) < 4) ? 1 : 2) : 0;
      int cct = (wt & 1) ? (((t & 7) < 4) ? 1 : 2) : 0;
      if (rci * 3 + cci != rct * 3 + cct) v -= 100.0f;
    }
    tbl[(h * 4 + wt) * 6400 + idx] = v;
  }
}

// LN1 + cyclic shift + window partition + time-token append -> xw bf16 (66560 x 512)
__global__ __launch_bounds__(256) void ln1_window_kernel(
    const float* __restrict__ x, const float* __restrict__ gamma,
    const float* __restrict__ beta, const float* __restrict__ t,
    bf16* __restrict__ xw)
{
  long r = (long)blockIdx.x * 4 + (threadIdx.x >> 6);   // 0..66559
  int lane = threadIdx.x & 63;
  int wb = (int)(r / NTOK), i = (int)(r % NTOK);
  int b = wb >> 6, w = wb & 63;
  bf16* out = xw + r * 512 + lane * 8;
  if (i == 64) {
    const float* tr = t + b * 512 + lane * 8;
    short8 o;
    #pragma unroll
    for (int e = 0; e < 8; ++e) o[e] = f2s(tr[e]);
    *(short8*)out = o;
    return;
  }
  int wh = w >> 3, ww = w & 7, ih = i >> 3, iw = i & 7;
  int hsrc = ((wh * 8 + ih) + 4) & 63;
  int wsrc = ((ww * 8 + iw) + 4) & 63;
  const float* xr = x + ((long)b * 4096 + hsrc * 64 + wsrc) * 512 + lane * 8;
  float v[8];
  *(f32x4*)&v[0] = *(const f32x4*)xr;
  *(f32x4*)&v[4] = *(const f32x4*)(xr + 4);
  float m, rstd;
  wave_stats512(v, m, rstd);
  const float* g = gamma + lane * 8;
  const float* bt = beta + lane * 8;
  short8 o;
  #pragma unroll
  for (int e = 0; e < 8; ++e) o[e] = f2s((v[e] - m) * rstd * g[e] + bt[e]);
  *(short8*)out = o;
}

// LN2 over x1 rows (65536 x 512) -> bf16 ; one WAVE per row
__global__ __launch_bounds__(256) void ln2_kernel(
    const float* __restrict__ x1, const float* __restrict__ gamma,
    const float* __restrict__ beta, bf16* __restrict__ out)
{
  long r = (long)blockIdx.x * 4 + (threadIdx.x >> 6);
  int lane = threadIdx.x & 63;
  const float* xr = x1 + r * 512 + lane * 8;
  float v[8];
  *(f32x4*)&v[0] = *(const f32x4*)xr;
  *(f32x4*)&v[4] = *(const f32x4*)(xr + 4);
  float m, rstd;
  wave_stats512(v, m, rstd);
  const float* g = gamma + lane * 8;
  const float* bt = beta + lane * 8;
  short8 o;
  #pragma unroll
  for (int e = 0; e < 8; ++e) o[e] = f2s((v[e] - m) * rstd * g[e] + bt[e]);
  *(short8*)(out + r * 512 + lane * 8) = o;
}

// ---------------- 256x256 8-wave MFMA GEMM, raw-barrier pipelined ----------------
template<int EPI>
__global__ __launch_bounds__(512, 2) void gemm8_kernel(
    const bf16* __restrict__ A, const bf16* __restrict__ Bt,
    const float* __restrict__ bias, int N, int K,
    bf16* __restrict__ outB, float* __restrict__ outF,
    const float* __restrict__ xin, int rowOffset)
{
  __shared__ bf16 lds[2][2][256 * 64];
  const int tid = threadIdx.x;
  const int lane = tid & 63;
  const int wv = tid >> 6;             // 0..7
  const int wm = wv >> 2, wn = wv & 3; // 2 x 4
  const int fr = lane & 15, fg = lane >> 4;
  const long row0 = (long)blockIdx.y * 256;
  const long col0 = (long)blockIdx.x * 256;

  const int srow = lane >> 3;                 // 0..7
  const int sslot = (lane & 7) ^ srow;        // pre-swizzled global 16B slot
  const int c0 = wv * 2;

  f32x4 acc[8][4] = {};
  const int nkt = K >> 6;

  auto stage_tile = [&](int buf, int gk) {
    #pragma unroll
    for (int q2 = 0; q2 < 2; ++q2) {
      int rr = (c0 + q2) * 8;
      const bf16* pA = A + (row0 + rr + srow) * (long)K + gk + sslot * 8;
      const bf16* pB = Bt + (col0 + rr + srow) * (long)K + gk + sslot * 8;
      bf16* dA = &lds[buf][0][rr * 64];
      bf16* dB = &lds[buf][1][rr * 64];
      async_lds16(pA, dA);
      async_lds16(pA + (long)128 * K, dA + 128 * 64);
      async_lds16(pB, dB);
      async_lds16(pB + (long)128 * K, dB + 128 * 64);
    }
  };
  auto frag = [&](const bf16* tile, int row, int slotB) -> short8 {
    return *(const short8*)((const char*)tile + row * 128 + ((slotB ^ (row & 7)) << 4));
  };

  stage_tile(0, 0);
  asm volatile("s_waitcnt vmcnt(0)" ::: "memory");
  asm volatile("s_barrier" ::: "memory");

  for (int i = 0; i < nkt; ++i) {
    const bf16* At = &lds[i & 1][0][0];
    const bf16* Bl = &lds[i & 1][1][0];
    const bool st = (i + 1 < nkt);
    short8 breg[4][2];
    #pragma unroll
    for (int ph = 0; ph < 4; ++ph) {
      short8 a[2][2];
      #pragma unroll
      for (int m2 = 0; m2 < 2; ++m2)
        #pragma unroll
        for (int ks = 0; ks < 2; ++ks)
          a[m2][ks] = frag(At, wm * 128 + (ph * 2 + m2) * 16 + fr, ks * 4 + fg);
      if (ph == 0) {
        #pragma unroll
        for (int ni = 0; ni < 4; ++ni)
          #pragma unroll
          for (int ks = 0; ks < 2; ++ks)
            breg[ni][ks] = frag(Bl, wn * 64 + ni * 16 + fr, ks * 4 + fg);
        if (st) stage_tile((i & 1) ^ 1, (i + 1) << 6);
      }
      asm volatile("s_barrier" ::: "memory");
      __builtin_amdgcn_s_setprio(1);
      #pragma unroll
      for (int m2 = 0; m2 < 2; ++m2)
        #pragma unroll
        for (int ni = 0; ni < 4; ++ni)
          #pragma unroll
          for (int ks = 0; ks < 2; ++ks)
            acc[ph * 2 + m2][ni] = __builtin_amdgcn_mfma_f32_16x16x32_bf16(
                a[m2][ks], breg[ni][ks], acc[ph * 2 + m2][ni], 0, 0, 0);
      __builtin_amdgcn_s_setprio(0);
      if (ph == 3 && st) asm volatile("s_waitcnt vmcnt(0)" ::: "memory");
      asm volatile("s_barrier" ::: "memory");
    }
  }

  // epilogue
  float bs[4];
  #pragma unroll
  for (int ni = 0; ni < 4; ++ni) bs[ni] = bias[col0 + wn * 64 + ni * 16 + fr];
  #pragma unroll
  for (int mi = 0; mi < 8; ++mi) {
    #pragma unroll
    for (int j = 0; j < 4; ++j) {
      long rr = row0 + wm * 128 + mi * 16 + fg * 4 + j;
      if (EPI == 2) {
        int grow = rowOffset + (int)rr;
        int ii = grow % NTOK;
        if (ii == 64) continue;
        int wb = grow / NTOK;
        int b = wb >> 6, w = wb & 63;
        int wh = w >> 3, ww = w & 7, ih = ii >> 3, iw = ii & 7;
        int hh   = ((wh * 8 + ih) + 4) & 63;
        int wcol = ((ww * 8 + iw) + 4) & 63;
        long orow = ((long)b * 4096 + hh * 64 + wcol) * 512;
        #pragma unroll
        for (int ni = 0; ni < 4; ++ni) {
          long o = orow + col0 + wn * 64 + ni * 16 + fr;
          outF[o] = xin[o] + acc[mi][ni][j] + bs[ni];
        }
      } else {
        #pragma unroll
        for (int ni = 0; ni < 4; ++ni) {
          long cc = col0 + wn * 64 + ni * 16 + fr;
          float v = acc[mi][ni][j] + bs[ni];
          if (EPI == 0) {
            outB[rr * N + cc] = __float2bfloat16(v);
          } else if (EPI == 1) {
            float g = 0.5f * v * (1.0f + erff(v * 0.70710678118654752f));
            outB[rr * N + cc] = __float2bfloat16(g);
          } else {
            long o = rr * N + cc;
            outF[o] = outF[o] + v;
          }
        }
      }
    }
  }
}

// ---------------- MFMA windowed attention: one wave per (window-batch, head) ----
// S^T = K @ Q^T (A=K frags, B=Q frags, direct global short8 loads).
// ALL row indices clamped to 64 (padded rows replicate the time token): padded
// keys are killed by the -1e30 table entries (exp -> exactly 0), padded query
// columns are discarded at store, padded V rows multiply exactly-0 P. P pad
// columns t in [80,104) are zeroed explicitly (PV k-range covers t<96).
__global__ __launch_bounds__(64, 2) void attn_mfma_kernel(
    const bf16* __restrict__ qkv, bf16* __restrict__ attnO,
    const float* __restrict__ tbl, int wb0)
{
  __shared__ bf16 P[80 * 104];
  const int lwb = blockIdx.x, h = blockIdx.y;
  const int lane = threadIdx.x;
  const int fr = lane & 15, g = lane >> 4;
  const float scale = 0.17677669529663687f;   // 1/sqrt(32)
  const bf16* base = qkv + (long)lwb * 65 * 1536 + h * 32 + g * 8;

  // zero P pad slots (t in [80,104)): 80 rows x 3 x 16B slots
  for (int idx = lane; idx < 240; idx += 64) {
    int i = idx / 3, s = idx % 3;
    *(short8*)&P[i * 104 + 80 + s * 8] = (short8){0, 0, 0, 0, 0, 0, 0, 0};
  }

  // Q B-frags (n = query i = 16tn+fr clamped, k = d = 8g+e)
  short8 bq[5];
  #pragma unroll
  for (int tn = 0; tn < 5; ++tn) {
    int qr = tn * 16 + fr; qr = qr > 64 ? 64 : qr;
    bq[tn] = *(const short8*)(base + (long)qr * 1536);
  }

  // S^T = K @ Q^T : acc[tm][tn], lane holds (t = 16tm+4g+r, i = 16tn+fr)
  f32x4 acc[5][5];
  #pragma unroll
  for (int tm = 0; tm < 5; ++tm) {
    int kr = tm * 16 + fr; kr = kr > 64 ? 64 : kr;
    short8 ak = *(const short8*)(base + 512 + (long)kr * 1536);
    #pragma unroll
    for (int tn = 0; tn < 5; ++tn)
      acc[tm][tn] = __builtin_amdgcn_mfma_f32_16x16x32_bf16(
          ak, bq[tn], (f32x4){0.0f, 0.0f, 0.0f, 0.0f}, 0, 0, 0);
  }

  // bias+mask + softmax (over t) + P write
  const int w = (wb0 + lwb) & 63;
  const int wt = (((w >> 3) == 7) ? 2 : 0) + (((w & 7) == 7) ? 1 : 0);
  const float* tp = tbl + (h * 4 + wt) * 6400;
  #pragma unroll
  for (int tn = 0; tn < 5; ++tn) {
    const int i = tn * 16 + fr;
    const float* ti = tp + i * 80 + g * 4;
    float m = -3.0e38f;
    #pragma unroll
    for (int tm = 0; tm < 5; ++tm) {
      f32x4 bv = *(const f32x4*)(ti + tm * 16);
      #pragma unroll
      for (int r = 0; r < 4; ++r) {
        float s = fmaf(acc[tm][tn][r], scale, bv[r]);
        acc[tm][tn][r] = s;
        m = fmaxf(m, s);
      }
    }
    m = fmaxf(m, __shfl_xor(m, 16));
    m = fmaxf(m, __shfl_xor(m, 32));
    float l = 0.0f;
    #pragma unroll
    for (int tm = 0; tm < 5; ++tm)
      #pragma unroll
      for (int r = 0; r < 4; ++r) {
        float e = __expf(acc[tm][tn][r] - m);
        acc[tm][tn][r] = e;
        l += e;
      }
    l += __shfl_xor(l, 16);
    l += __shfl_xor(l, 32);
    float inv = 1.0f / l;
    #pragma unroll
    for (int tm = 0; tm < 5; ++tm) {
      short4_t pk;
      #pragma unroll
      for (int r = 0; r < 4; ++r) pk[r] = f2s(acc[tm][tn][r] * inv);
      *(short4_t*)&P[i * 104 + tm * 16 + g * 4] = pk;
    }
  }

  // O^T = V^T @ P : oacc[ma][tn], lane holds (d = 16ma+4g+r, i = 16tn+fr)
  const bf16* vbase = qkv + (long)lwb * 65 * 1536 + 1024 + h * 32;
  f32x4 oacc[2][5] = {};
  #pragma unroll
  for (int kt = 0; kt < 3; ++kt) {
    short8 bp[5];
    #pragma unroll
    for (int tn = 0; tn < 5; ++tn)
      bp[tn] = *(const short8*)&P[(tn * 16 + fr) * 104 + kt * 32 + g * 8];
    #pragma unroll
    for (int ma = 0; ma < 2; ++ma) {
      short8 av;
      #pragma unroll
      for (int e = 0; e < 8; ++e) {
        int vr = kt * 32 + g * 8 + e; vr = vr > 64 ? 64 : vr;
        av[e] = *(const short*)(vbase + (long)vr * 1536 + ma * 16 + fr);
      }
      #pragma unroll
      for (int tn = 0; tn < 5; ++tn)
        oacc[ma][tn] = __builtin_amdgcn_mfma_f32_16x16x32_bf16(
            av, bp[tn], oacc[ma][tn], 0, 0, 0);
    }
  }

  // store O rows i<65: attnO[(wb*65+i)*512 + h*32 + d]
  #pragma unroll
  for (int tn = 0; tn < 5; ++tn) {
    int i = tn * 16 + fr;
    if (i < 65) {
      bf16* op = attnO + (long)(lwb * 65 + i) * 512 + h * 32 + g * 4;
      #pragma unroll
      for (int ma = 0; ma < 2; ++ma) {
        short4_t o4;
        #pragma unroll
        for (int r = 0; r < 4; ++r) o4[r] = f2s(oacc[ma][tn][r]);
        *(short4_t*)(op + ma * 16) = o4;
      }
    }
  }
}

// ---------------- host ----------------

extern "C" void kernel_launch(void* const* d_in, const int* in_sizes, int n_in,
                              void* d_out, int out_size, void* d_ws, size_t ws_size,
                              hipStream_t stream)
{
  const float* x      = (const float*)d_in[0];
  const float* emb    = (const float*)d_in[1];
  const float* gamma1 = (const float*)d_in[2];
  const float* beta1  = (const float*)d_in[3];
  const float* W_emb  = (const float*)d_in[4];
  const float* b_emb  = (const float*)d_in[5];
  const float* W_qkv  = (const float*)d_in[6];
  const float* b_qkv  = (const float*)d_in[7];
  const float* btab   = (const float*)d_in[8];
  const float* W_proj = (const float*)d_in[9];
  const float* b_proj = (const float*)d_in[10];
  const float* gamma2 = (const float*)d_in[11];
  const float* beta2  = (const float*)d_in[12];
  const float* W1     = (const float*)d_in[13];
  const float* b1     = (const float*)d_in[14];
  const float* W2     = (const float*)d_in[15];
  const float* b2     = (const float*)d_in[16];
  float* out = (float*)d_out;
  (void)n_in; (void)in_sizes; (void)out_size;

  char* ws = (char*)d_ws;
  size_t off = 0;
  auto alloc = [&](size_t bytes) -> char* {
    char* p = ws + off;
    off += (bytes + 255) & ~(size_t)255;
    return p;
  };
  bf16* wt_qkv  = (bf16*)alloc((size_t)1536 * 512 * 2);
  bf16* wt_proj = (bf16*)alloc((size_t)512 * 512 * 2);
  bf16* wt1     = (bf16*)alloc((size_t)2048 * 512 * 2);
  bf16* wt2     = (bf16*)alloc((size_t)512 * 2048 * 2);
  float* tvec   = (float*)alloc((size_t)16 * 512 * 4);
  float* tbl    = (float*)alloc((size_t)16 * 4 * 6400 * 4);

  const size_t sz_xw    = (size_t)TOTROWS * 512 * 2;
  const size_t sz_qkv   = (size_t)TOTROWS * 1536 * 2;
  const size_t sz_attnO = (size_t)TOTROWS * 512 * 2;
  const bool big = ws_size >= off + sz_xw + sz_qkv + sz_attnO + (4u << 20);

  // weight prep (common)
  transpose_cast_kernel<<<dim3(1536 / 32, 512 / 32), dim3(32, 8), 0, stream>>>(W_qkv, wt_qkv, 512, 1536);
  transpose_cast_kernel<<<dim3(512 / 32, 512 / 32),  dim3(32, 8), 0, stream>>>(W_proj, wt_proj, 512, 512);
  transpose_cast_kernel<<<dim3(2048 / 32, 512 / 32), dim3(32, 8), 0, stream>>>(W1, wt1, 512, 2048);
  transpose_cast_kernel<<<dim3(512 / 32, 2048 / 32), dim3(32, 8), 0, stream>>>(W2, wt2, 2048, 512);
  time_emb_kernel<<<dim3(16, 2), 256, 0, stream>>>(emb, W_emb, b_emb, tvec);
  bias_mask_kernel<<<dim3(16, 4), 256, 0, stream>>>(btab, tbl);

  if (big) {
    bf16* xw    = (bf16*)alloc(sz_xw);
    bf16* qkv   = (bf16*)alloc(sz_qkv);
    bf16* attnO = (bf16*)alloc(sz_attnO);
    bf16* ln2b  = xw;          // xw dead after qkv GEMM
    bf16* h     = qkv;         // qkv dead after attention

    ln1_window_kernel<<<TOTROWS / 4, 256, 0, stream>>>(x, gamma1, beta1, tvec, xw);
    gemm8_kernel<0><<<dim3(6, 260), 512, 0, stream>>>(
        xw, wt_qkv, b_qkv, 1536, 512, qkv, nullptr, nullptr, 0);
    attn_mfma_kernel<<<dim3(NB * NWIN, HEADS_), 64, 0, stream>>>(qkv, attnO, tbl, 0);
    gemm8_kernel<2><<<dim3(2, 260), 512, 0, stream>>>(
        attnO, wt_proj, b_proj, 512, 512, nullptr, out, x, 0);
    ln2_kernel<<<65536 / 4, 256, 0, stream>>>(out, gamma2, beta2, ln2b);
    gemm8_kernel<1><<<dim3(8, 256), 512, 0, stream>>>(
        ln2b, wt1, b1, 2048, 512, h, nullptr, nullptr, 0);
    gemm8_kernel<3><<<dim3(2, 256), 512, 0, stream>>>(
        h, wt2, b2, 512, 2048, nullptr, out, nullptr, 0);
  } else {
    // chunked fallback
    char* regionA = alloc(sz_xw);                     // xw, later ln2b
    bf16* xw   = (bf16*)regionA;
    bf16* ln2b = (bf16*)regionA;
    bf16* qkv_c = (bf16*)alloc((size_t)8448 * 1536 * 2);  // padded to 33*256 rows
    char* regionB = alloc(sz_attnO);                  // attnO, later h_c
    bf16* attnO = (bf16*)regionB;
    bf16* h_c   = (bf16*)regionB;

    ln1_window_kernel<<<TOTROWS / 4, 256, 0, stream>>>(x, gamma1, beta1, tvec, xw);
    for (int ac = 0; ac < 8; ++ac) {
      long r0 = (long)ac * ATT_CHUNK_ROWS;
      gemm8_kernel<0><<<dim3(6, 33), 512, 0, stream>>>(
          xw + r0 * 512, wt_qkv, b_qkv, 1536, 512, qkv_c, nullptr, nullptr, 0);
      attn_mfma_kernel<<<dim3(ATT_CHUNK_WB, HEADS_), 64, 0, stream>>>(
          qkv_c, attnO + r0 * 512, tbl, ac * ATT_CHUNK_WB);
    }
    gemm8_kernel<2><<<dim3(2, 260), 512, 0, stream>>>(
        attnO, wt_proj, b_proj, 512, 512, nullptr, out, x, 0);
    ln2_kernel<<<65536 / 4, 256, 0, stream>>>(out, gamma2, beta2, ln2b);
    for (int mc = 0; mc < 4; ++mc) {
      long r0 = (long)mc * MLP_CHUNK_ROWS;
      gemm8_kernel<1><<<dim3(8, 64), 512, 0, stream>>>(
          ln2b + r0 * 512, wt1, b1, 2048, 512, h_c, nullptr, nullptr, 0);
      gemm8_kernel<3><<<dim3(2, 64), 512, 0, stream>>>(
          h_c, wt2, b2, 512, 2048, nullptr, out + r0 * 512, nullptr, 0);
    }
  }
}

// Round 7
// 896.325 us; speedup vs baseline: 2.8203x; 1.0521x over previous
//
#include <hip/hip_runtime.h>
#include <hip/hip_bf16.h>

typedef __hip_bfloat16 bf16;
typedef short short4_t __attribute__((ext_vector_type(4)));
typedef short short8 __attribute__((ext_vector_type(8)));
typedef float f32x4 __attribute__((ext_vector_type(4)));

// static config
#define DIMC 512
#define HEADS_ 16
#define NTOK 65        // 64 window tokens + 1 time token
#define NWIN 64
#define NB 16
#define HID 2048
#define TOTROWS 66560  // 16*64*65
#define ATT_CHUNK_WB 128                      // window-batches per attention chunk
#define ATT_CHUNK_ROWS (ATT_CHUNK_WB * NTOK)  // 8320

// ---------------- helpers ----------------

__device__ __forceinline__ float b2f(short s) {
  unsigned int u = ((unsigned int)(unsigned short)s) << 16;
  float f; __builtin_memcpy(&f, &u, 4); return f;
}
__device__ __forceinline__ short f2s(float f) {
  bf16 b = __float2bfloat16(f);
  short s; __builtin_memcpy(&s, &b, 2); return s;
}

// async global->LDS, 16B per lane; LDS dest is wave-uniform base + lane*16
__device__ __forceinline__ void async_lds16(const bf16* g, bf16* l) {
  __builtin_amdgcn_global_load_lds(
      (const __attribute__((address_space(1))) unsigned int*)g,
      (__attribute__((address_space(3))) unsigned int*)l,
      16, 0, 0);
}

// per-wave LN stats over 512 elems (8 per lane)
__device__ __forceinline__ void wave_stats512(const float* v, float& m, float& rstd)
{
  float s = 0.0f, ss = 0.0f;
  #pragma unroll
  for (int e = 0; e < 8; ++e) { s += v[e]; ss += v[e] * v[e]; }
  #pragma unroll
  for (int o = 1; o < 64; o <<= 1) { s += __shfl_xor(s, o); ss += __shfl_xor(ss, o); }
  m = s * (1.0f / 512.0f);
  rstd = rsqrtf(ss * (1.0f / 512.0f) - m * m + 1e-5f);
}

// tanh-form GELU (max abs err ~3e-4, well under bf16 rounding)
__device__ __forceinline__ float gelu_t(float v) {
  float u = v + 0.044715f * v * v * v;
  float z2 = 1.5957691216f * fabsf(u);
  float t = __expf(-z2);
  float th = 1.0f - 2.0f * t / (1.0f + t);
  th = (u < 0.0f) ? -th : th;
  return 0.5f * v * (1.0f + th);
}

// ---------------- small kernels ----------------

__global__ __launch_bounds__(256) void time_emb_kernel(
    const float* __restrict__ emb, const float* __restrict__ W_emb,
    const float* __restrict__ b_emb, float* __restrict__ t)
{
  int b = blockIdx.x;
  int c = blockIdx.y * 256 + threadIdx.x;
  __shared__ float se[512];
  for (int k = threadIdx.x; k < 512; k += 256) {
    float e = emb[b * 512 + k];
    se[k] = e / (1.0f + expf(-e));
  }
  __syncthreads();
  float acc = b_emb[c];
  for (int k = 0; k < 512; ++k) acc += se[k] * W_emb[k * 512 + c];
  t[b * 512 + c] = acc;
}

// W (Kd x Nd) f32 -> Wt (Nd x Kd) bf16
__global__ void transpose_cast_kernel(const float* __restrict__ W, bf16* __restrict__ Wt,
                                      int Kd, int Nd)
{
  __shared__ float tile[32][33];
  int n0 = blockIdx.x * 32, k0 = blockIdx.y * 32;
  for (int r = threadIdx.y; r < 32; r += 8)
    tile[r][threadIdx.x] = W[(long)(k0 + r) * Nd + n0 + threadIdx.x];
  __syncthreads();
  for (int r = threadIdx.y; r < 32; r += 8)
    Wt[(long)(n0 + r) * Kd + k0 + threadIdx.x] = __float2bfloat16(tile[threadIdx.x][r]);
}

// combined bias+mask table: tbl[h][wtype][i(query) 80][t(key) 80] f32
__global__ __launch_bounds__(256) void bias_mask_kernel(
    const float* __restrict__ btab, float* __restrict__ tbl)
{
  int h = blockIdx.x, wt = blockIdx.y;
  for (int idx = threadIdx.x; idx < 6400; idx += 256) {
    int i = idx / 80, t = idx % 80;
    float v;
    if (t >= 65) v = -1e30f;
    else if (i >= 64 || t == 64) v = 0.0f;
    else {
      int rel = (((i >> 3) - (t >> 3) + 7) * 15) + ((i & 7) - (t & 7) + 7);
      v = btab[rel * HEADS_ + h];
      int rci = (wt & 2) ? (((i >> 3) < 4) ? 1 : 2) : 0;
      int cci = (wt & 1) ? (((i & 7) < 4) ? 1 : 2) : 0;
      int rct = (wt & 2) ? (((t >> 3) < 4) ? 1 : 2) : 0;
      int cct = (wt & 1) ? (((t & 7) < 4) ? 1 : 2) : 0;
      if (rci * 3 + cci != rct * 3 + cct) v -= 100.0f;
    }
    tbl[(h * 4 + wt) * 6400 + idx] = v;
  }
}

// LN1 + cyclic shift + window partition + time-token append -> xw bf16 (66560 x 512)
__global__ __launch_bounds__(256) void ln1_window_kernel(
    const float* __restrict__ x, const float* __restrict__ gamma,
    const float* __restrict__ beta, const float* __restrict__ t,
    bf16* __restrict__ xw)
{
  long r = (long)blockIdx.x * 4 + (threadIdx.x >> 6);   // 0..66559
  int lane = threadIdx.x & 63;
  int wb = (int)(r / NTOK), i = (int)(r % NTOK);
  int b = wb >> 6, w = wb & 63;
  bf16* out = xw + r * 512 + lane * 8;
  if (i == 64) {
    const float* tr = t + b * 512 + lane * 8;
    short8 o;
    #pragma unroll
    for (int e = 0; e < 8; ++e) o[e] = f2s(tr[e]);
    *(short8*)out = o;
    return;
  }
  int wh = w >> 3, ww = w & 7, ih = i >> 3, iw = i & 7;
  int hsrc = ((wh * 8 + ih) + 4) & 63;
  int wsrc = ((ww * 8 + iw) + 4) & 63;
  const float* xr = x + ((long)b * 4096 + hsrc * 64 + wsrc) * 512 + lane * 8;
  float v[8];
  *(f32x4*)&v[0] = *(const f32x4*)xr;
  *(f32x4*)&v[4] = *(const f32x4*)(xr + 4);
  float m, rstd;
  wave_stats512(v, m, rstd);
  const float* g = gamma + lane * 8;
  const float* bt = beta + lane * 8;
  short8 o;
  #pragma unroll
  for (int e = 0; e < 8; ++e) o[e] = f2s((v[e] - m) * rstd * g[e] + bt[e]);
  *(short8*)out = o;
}

// LN2 over x1 rows (65536 x 512) -> bf16 ; one WAVE per row
__global__ __launch_bounds__(256) void ln2_kernel(
    const float* __restrict__ x1, const float* __restrict__ gamma,
    const float* __restrict__ beta, bf16* __restrict__ out)
{
  long r = (long)blockIdx.x * 4 + (threadIdx.x >> 6);
  int lane = threadIdx.x & 63;
  const float* xr = x1 + r * 512 + lane * 8;
  float v[8];
  *(f32x4*)&v[0] = *(const f32x4*)xr;
  *(f32x4*)&v[4] = *(const f32x4*)(xr + 4);
  float m, rstd;
  wave_stats512(v, m, rstd);
  const float* g = gamma + lane * 8;
  const float* bt = beta + lane * 8;
  short8 o;
  #pragma unroll
  for (int e = 0; e < 8; ++e) o[e] = f2s((v[e] - m) * rstd * g[e] + bt[e]);
  *(short8*)(out + r * 512 + lane * 8) = o;
}

// ---------------- 128x256 MFMA GEMM, BK=32, dbuf, 2 blocks/CU ----------------
// C = A(MxK) @ Bt(NxK)^T + bias. 512 threads = 8 waves (2M x 4N), per-wave 64x64.
// LDS 48 KiB: lA[2][128*32], lB[2][256*32], 64B rows of 4 x 16B slots, swizzled
// slot' = slot ^ ((row>>1)&3)  (2-way bank alias = free). Staged via
// global_load_lds w=16 (linear dest, pre-swizzled global source).
// 1-D grid with bijective XCD swizzle; x (col-block) fastest.
// EPI 0: bf16 store | 1: gelu->bf16 | 2: proj residual+unshift scatter | 3: f32 +=
template<int EPI>
__global__ __launch_bounds__(512, 4) void gemmk_kernel(
    const bf16* __restrict__ A, const bf16* __restrict__ Bt,
    const float* __restrict__ bias, int N, int K, int nx,
    bf16* __restrict__ outB, float* __restrict__ outF,
    const float* __restrict__ xin, int rowOffset)
{
  __shared__ bf16 lA[2][128 * 32];
  __shared__ bf16 lB[2][256 * 32];
  const int tid = threadIdx.x;
  const int lane = tid & 63, wv = tid >> 6;
  const int wm = wv >> 2, wn = wv & 3;       // 2 x 4
  const int fr = lane & 15, fg = lane >> 4;

  // bijective XCD swizzle (m204): works for any nwg
  const int nwg = gridDim.x, bid = blockIdx.x;
  const int q = nwg >> 3, rr8 = nwg & 7;
  const int xcd = bid & 7, idx = bid >> 3;
  const int sid = (xcd < rr8 ? xcd * (q + 1) : rr8 * (q + 1) + (xcd - rr8) * q) + idx;
  const long row0 = (long)(sid / nx) * 128;
  const long col0 = (long)(sid % nx) * 256;

  // staging geometry: per thread one 16B slot; instruction covers 16 rows
  const int rl = lane >> 2, sp = lane & 3;
  const int s = sp ^ ((rl >> 1) & 3);        // pre-swizzled global slot
  const bf16* gA  = A  + (row0 + wv * 16 + rl) * (long)K + s * 8;
  const bf16* gB0 = Bt + (col0 + wv * 16 + rl) * (long)K + s * 8;
  const bf16* gB1 = Bt + (col0 + 128 + wv * 16 + rl) * (long)K + s * 8;

  f32x4 acc[4][4] = {};
  const int nkt = K >> 5;
  const int swr = (fg ^ ((fr >> 1) & 3)) << 4;   // read-side swizzled slot byte

  auto stage = [&](int buf, int kt) {
    async_lds16(gA + kt, &lA[buf][wv * 512]);
    async_lds16(gB0 + kt, &lB[buf][wv * 512]);
    async_lds16(gB1 + kt, &lB[buf][4096 + wv * 512]);
  };

  stage(0, 0);
  __syncthreads();

  for (int t = 0; t < nkt; ++t) {
    const int buf = t & 1;
    if (t + 1 < nkt) stage(buf ^ 1, (t + 1) << 5);
    short8 af[4], bfv[4];
    #pragma unroll
    for (int mi = 0; mi < 4; ++mi)
      af[mi] = *(const short8*)((const char*)&lA[buf][0] + (wm * 64 + mi * 16 + fr) * 64 + swr);
    #pragma unroll
    for (int ni = 0; ni < 4; ++ni)
      bfv[ni] = *(const short8*)((const char*)&lB[buf][0] + (wn * 64 + ni * 16 + fr) * 64 + swr);
    __builtin_amdgcn_s_setprio(1);
    #pragma unroll
    for (int mi = 0; mi < 4; ++mi)
      #pragma unroll
      for (int ni = 0; ni < 4; ++ni)
        acc[mi][ni] = __builtin_amdgcn_mfma_f32_16x16x32_bf16(af[mi], bfv[ni], acc[mi][ni], 0, 0, 0);
    __builtin_amdgcn_s_setprio(0);
    __syncthreads();   // drains vmcnt(0)+lgkm: next buf ready; reads done before overwrite
  }

  // epilogue
  float bs[4];
  #pragma unroll
  for (int ni = 0; ni < 4; ++ni) bs[ni] = bias[col0 + wn * 64 + ni * 16 + fr];
  #pragma unroll
  for (int mi = 0; mi < 4; ++mi) {
    #pragma unroll
    for (int j = 0; j < 4; ++j) {
      long rr = row0 + wm * 64 + mi * 16 + fg * 4 + j;
      if (EPI == 2) {
        int grow = rowOffset + (int)rr;
        int ii = grow % NTOK;
        if (ii == 64) continue;
        int wb = grow / NTOK;
        int b = wb >> 6, w = wb & 63;
        int wh = w >> 3, ww = w & 7, ih = ii >> 3, iw = ii & 7;
        int hh   = ((wh * 8 + ih) + 4) & 63;
        int wcol = ((ww * 8 + iw) + 4) & 63;
        long orow = ((long)b * 4096 + hh * 64 + wcol) * 512;
        #pragma unroll
        for (int ni = 0; ni < 4; ++ni) {
          long o = orow + col0 + wn * 64 + ni * 16 + fr;
          outF[o] = xin[o] + acc[mi][ni][j] + bs[ni];
        }
      } else {
        #pragma unroll
        for (int ni = 0; ni < 4; ++ni) {
          long cc = col0 + wn * 64 + ni * 16 + fr;
          float v = acc[mi][ni][j] + bs[ni];
          if (EPI == 0) {
            outB[rr * N + cc] = __float2bfloat16(v);
          } else if (EPI == 1) {
            outB[rr * N + cc] = __float2bfloat16(gelu_t(v));
          } else {
            long o = rr * N + cc;
            outF[o] = outF[o] + v;
          }
        }
      }
    }
  }
}

// ---------------- MFMA windowed attention: one wave per (window-batch, head) ----
__global__ __launch_bounds__(64, 2) void attn_mfma_kernel(
    const bf16* __restrict__ qkv, bf16* __restrict__ attnO,
    const float* __restrict__ tbl, int wb0)
{
  __shared__ bf16 P[80 * 104];
  const int lwb = blockIdx.x, h = blockIdx.y;
  const int lane = threadIdx.x;
  const int fr = lane & 15, g = lane >> 4;
  const float scale = 0.17677669529663687f;   // 1/sqrt(32)
  const bf16* base = qkv + (long)lwb * 65 * 1536 + h * 32 + g * 8;

  // zero P pad slots (t in [80,104))
  for (int idx = lane; idx < 240; idx += 64) {
    int i = idx / 3, sl = idx % 3;
    *(short8*)&P[i * 104 + 80 + sl * 8] = (short8){0, 0, 0, 0, 0, 0, 0, 0};
  }

  short8 bq[5];
  #pragma unroll
  for (int tn = 0; tn < 5; ++tn) {
    int qr = tn * 16 + fr; qr = qr > 64 ? 64 : qr;
    bq[tn] = *(const short8*)(base + (long)qr * 1536);
  }

  f32x4 acc[5][5];
  #pragma unroll
  for (int tm = 0; tm < 5; ++tm) {
    int kr = tm * 16 + fr; kr = kr > 64 ? 64 : kr;
    short8 ak = *(const short8*)(base + 512 + (long)kr * 1536);
    #pragma unroll
    for (int tn = 0; tn < 5; ++tn)
      acc[tm][tn] = __builtin_amdgcn_mfma_f32_16x16x32_bf16(
          ak, bq[tn], (f32x4){0.0f, 0.0f, 0.0f, 0.0f}, 0, 0, 0);
  }

  const int w = (wb0 + lwb) & 63;
  const int wt = (((w >> 3) == 7) ? 2 : 0) + (((w & 7) == 7) ? 1 : 0);
  const float* tp = tbl + (h * 4 + wt) * 6400;
  #pragma unroll
  for (int tn = 0; tn < 5; ++tn) {
    const int i = tn * 16 + fr;
    const float* ti = tp + i * 80 + g * 4;
    float m = -3.0e38f;
    #pragma unroll
    for (int tm = 0; tm < 5; ++tm) {
      f32x4 bv = *(const f32x4*)(ti + tm * 16);
      #pragma unroll
      for (int r = 0; r < 4; ++r) {
        float sv = fmaf(acc[tm][tn][r], scale, bv[r]);
        acc[tm][tn][r] = sv;
        m = fmaxf(m, sv);
      }
    }
    m = fmaxf(m, __shfl_xor(m, 16));
    m = fmaxf(m, __shfl_xor(m, 32));
    float l = 0.0f;
    #pragma unroll
    for (int tm = 0; tm < 5; ++tm)
      #pragma unroll
      for (int r = 0; r < 4; ++r) {
        float e = __expf(acc[tm][tn][r] - m);
        acc[tm][tn][r] = e;
        l += e;
      }
    l += __shfl_xor(l, 16);
    l += __shfl_xor(l, 32);
    float inv = 1.0f / l;
    #pragma unroll
    for (int tm = 0; tm < 5; ++tm) {
      short4_t pk;
      #pragma unroll
      for (int r = 0; r < 4; ++r) pk[r] = f2s(acc[tm][tn][r] * inv);
      *(short4_t*)&P[i * 104 + tm * 16 + g * 4] = pk;
    }
  }

  const bf16* vbase = qkv + (long)lwb * 65 * 1536 + 1024 + h * 32;
  f32x4 oacc[2][5] = {};
  #pragma unroll
  for (int kt = 0; kt < 3; ++kt) {
    short8 bp[5];
    #pragma unroll
    for (int tn = 0; tn < 5; ++tn)
      bp[tn] = *(const short8*)&P[(tn * 16 + fr) * 104 + kt * 32 + g * 8];
    #pragma unroll
    for (int ma = 0; ma < 2; ++ma) {
      short8 av;
      #pragma unroll
      for (int e = 0; e < 8; ++e) {
        int vr = kt * 32 + g * 8 + e; vr = vr > 64 ? 64 : vr;
        av[e] = *(const short*)(vbase + (long)vr * 1536 + ma * 16 + fr);
      }
      #pragma unroll
      for (int tn = 0; tn < 5; ++tn)
        oacc[ma][tn] = __builtin_amdgcn_mfma_f32_16x16x32_bf16(
            av, bp[tn], oacc[ma][tn], 0, 0, 0);
    }
  }

  #pragma unroll
  for (int tn = 0; tn < 5; ++tn) {
    int i = tn * 16 + fr;
    if (i < 65) {
      bf16* op = attnO + (long)(lwb * 65 + i) * 512 + h * 32 + g * 4;
      #pragma unroll
      for (int ma = 0; ma < 2; ++ma) {
        short4_t o4;
        #pragma unroll
        for (int r = 0; r < 4; ++r) o4[r] = f2s(oacc[ma][tn][r]);
        *(short4_t*)(op + ma * 16) = o4;
      }
    }
  }
}

// ---------------- host ----------------

extern "C" void kernel_launch(void* const* d_in, const int* in_sizes, int n_in,
                              void* d_out, int out_size, void* d_ws, size_t ws_size,
                              hipStream_t stream)
{
  const float* x      = (const float*)d_in[0];
  const float* emb    = (const float*)d_in[1];
  const float* gamma1 = (const float*)d_in[2];
  const float* beta1  = (const float*)d_in[3];
  const float* W_emb  = (const float*)d_in[4];
  const float* b_emb  = (const float*)d_in[5];
  const float* W_qkv  = (const float*)d_in[6];
  const float* b_qkv  = (const float*)d_in[7];
  const float* btab   = (const float*)d_in[8];
  const float* W_proj = (const float*)d_in[9];
  const float* b_proj = (const float*)d_in[10];
  const float* gamma2 = (const float*)d_in[11];
  const float* beta2  = (const float*)d_in[12];
  const float* W1     = (const float*)d_in[13];
  const float* b1     = (const float*)d_in[14];
  const float* W2     = (const float*)d_in[15];
  const float* b2     = (const float*)d_in[16];
  float* out = (float*)d_out;
  (void)n_in; (void)in_sizes; (void)out_size;

  char* ws = (char*)d_ws;
  size_t off = 0;
  auto alloc = [&](size_t bytes) -> char* {
    char* p = ws + off;
    off += (bytes + 255) & ~(size_t)255;
    return p;
  };
  bf16* wt_qkv  = (bf16*)alloc((size_t)1536 * 512 * 2);
  bf16* wt_proj = (bf16*)alloc((size_t)512 * 512 * 2);
  bf16* wt1     = (bf16*)alloc((size_t)2048 * 512 * 2);
  bf16* wt2     = (bf16*)alloc((size_t)512 * 2048 * 2);
  float* tvec   = (float*)alloc((size_t)16 * 512 * 4);
  float* tbl    = (float*)alloc((size_t)16 * 4 * 6400 * 4);

  const size_t sz_xw    = (size_t)TOTROWS * 512 * 2;
  const size_t sz_qkv   = (size_t)TOTROWS * 1536 * 2;
  const size_t sz_attnO = (size_t)TOTROWS * 512 * 2;
  const bool big = ws_size >= off + sz_xw + sz_qkv + sz_attnO + (4u << 20);

  // weight prep (common)
  transpose_cast_kernel<<<dim3(1536 / 32, 512 / 32), dim3(32, 8), 0, stream>>>(W_qkv, wt_qkv, 512, 1536);
  transpose_cast_kernel<<<dim3(512 / 32, 512 / 32),  dim3(32, 8), 0, stream>>>(W_proj, wt_proj, 512, 512);
  transpose_cast_kernel<<<dim3(2048 / 32, 512 / 32), dim3(32, 8), 0, stream>>>(W1, wt1, 512, 2048);
  transpose_cast_kernel<<<dim3(512 / 32, 2048 / 32), dim3(32, 8), 0, stream>>>(W2, wt2, 2048, 512);
  time_emb_kernel<<<dim3(16, 2), 256, 0, stream>>>(emb, W_emb, b_emb, tvec);
  bias_mask_kernel<<<dim3(16, 4), 256, 0, stream>>>(btab, tbl);

  if (big) {
    bf16* xw    = (bf16*)alloc(sz_xw);
    bf16* qkv   = (bf16*)alloc(sz_qkv);
    bf16* attnO = (bf16*)alloc(sz_attnO);
    bf16* ln2b  = xw;          // xw dead after qkv GEMM
    bf16* h     = qkv;         // qkv dead after attention

    ln1_window_kernel<<<TOTROWS / 4, 256, 0, stream>>>(x, gamma1, beta1, tvec, xw);
    // qkv: M=66560, N=1536, K=512 -> grid 6 x 520
    gemmk_kernel<0><<<6 * 520, 512, 0, stream>>>(
        xw, wt_qkv, b_qkv, 1536, 512, 6, qkv, nullptr, nullptr, 0);
    attn_mfma_kernel<<<dim3(NB * NWIN, HEADS_), 64, 0, stream>>>(qkv, attnO, tbl, 0);
    // proj: M=66560, N=512, K=512 -> grid 2 x 520
    gemmk_kernel<2><<<2 * 520, 512, 0, stream>>>(
        attnO, wt_proj, b_proj, 512, 512, 2, nullptr, out, x, 0);
    ln2_kernel<<<65536 / 4, 256, 0, stream>>>(out, gamma2, beta2, ln2b);
    // mlp1: M=65536, N=2048, K=512 -> grid 8 x 512
    gemmk_kernel<1><<<8 * 512, 512, 0, stream>>>(
        ln2b, wt1, b1, 2048, 512, 8, h, nullptr, nullptr, 0);
    // mlp2: M=65536, N=512, K=2048 -> grid 2 x 512
    gemmk_kernel<3><<<2 * 512, 512, 0, stream>>>(
        h, wt2, b2, 512, 2048, 2, nullptr, out, nullptr, 0);
  } else {
    // chunked fallback
    char* regionA = alloc(sz_xw);                     // xw, later ln2b
    bf16* xw   = (bf16*)regionA;
    bf16* ln2b = (bf16*)regionA;
    bf16* qkv_c = (bf16*)alloc((size_t)ATT_CHUNK_ROWS * 1536 * 2);
    char* regionB = alloc(sz_attnO);                  // attnO, later h_c
    bf16* attnO = (bf16*)regionB;
    bf16* h_c   = (bf16*)regionB;

    ln1_window_kernel<<<TOTROWS / 4, 256, 0, stream>>>(x, gamma1, beta1, tvec, xw);
    for (int ac = 0; ac < 8; ++ac) {
      long r0 = (long)ac * ATT_CHUNK_ROWS;
      // 8320 rows = 65 row-blocks
      gemmk_kernel<0><<<6 * 65, 512, 0, stream>>>(
          xw + r0 * 512, wt_qkv, b_qkv, 1536, 512, 6, qkv_c, nullptr, nullptr, 0);
      attn_mfma_kernel<<<dim3(ATT_CHUNK_WB, HEADS_), 64, 0, stream>>>(
          qkv_c, attnO + r0 * 512, tbl, ac * ATT_CHUNK_WB);
    }
    gemmk_kernel<2><<<2 * 520, 512, 0, stream>>>(
        attnO, wt_proj, b_proj, 512, 512, 2, nullptr, out, x, 0);
    ln2_kernel<<<65536 / 4, 256, 0, stream>>>(out, gamma2, beta2, ln2b);
    for (int mc = 0; mc < 4; ++mc) {
      long r0 = (long)mc * 16384;
      gemmk_kernel<1><<<8 * 128, 512, 0, stream>>>(
          ln2b + r0 * 512, wt1, b1, 2048, 512, 8, h_c, nullptr, nullptr, 0);
      gemmk_kernel<3><<<2 * 128, 512, 0, stream>>>(
          h_c, wt2, b2, 512, 2048, 2, nullptr, out + r0 * 512, nullptr, 0);
    }
  }
}

// Round 8
// 879.215 us; speedup vs baseline: 2.8752x; 1.0195x over previous
//
#include <hip/hip_runtime.h>
#include <hip/hip_bf16.h>

typedef __hip_bfloat16 bf16;
typedef short short4_t __attribute__((ext_vector_type(4)));
typedef short short8 __attribute__((ext_vector_type(8)));
typedef float f32x4 __attribute__((ext_vector_type(4)));

// static config
#define DIMC 512
#define HEADS_ 16
#define NTOK 65        // 64 window tokens + 1 time token
#define NWIN 64
#define NB 16
#define HID 2048
#define TOTROWS 66560  // 16*64*65
#define ATT_CHUNK_WB 128                      // window-batches per attention chunk
#define ATT_CHUNK_ROWS (ATT_CHUNK_WB * NTOK)  // 8320

// ---------------- helpers ----------------

__device__ __forceinline__ float b2f(short s) {
  unsigned int u = ((unsigned int)(unsigned short)s) << 16;
  float f; __builtin_memcpy(&f, &u, 4); return f;
}
__device__ __forceinline__ short f2s(float f) {
  bf16 b = __float2bfloat16(f);
  short s; __builtin_memcpy(&s, &b, 2); return s;
}

// async global->LDS, 16B per lane; LDS dest is wave-uniform base + lane*16
__device__ __forceinline__ void async_lds16(const bf16* g, bf16* l) {
  __builtin_amdgcn_global_load_lds(
      (const __attribute__((address_space(1))) unsigned int*)g,
      (__attribute__((address_space(3))) unsigned int*)l,
      16, 0, 0);
}

// per-wave LN stats over 512 elems (8 per lane)
__device__ __forceinline__ void wave_stats512(const float* v, float& m, float& rstd)
{
  float s = 0.0f, ss = 0.0f;
  #pragma unroll
  for (int e = 0; e < 8; ++e) { s += v[e]; ss += v[e] * v[e]; }
  #pragma unroll
  for (int o = 1; o < 64; o <<= 1) { s += __shfl_xor(s, o); ss += __shfl_xor(ss, o); }
  m = s * (1.0f / 512.0f);
  rstd = rsqrtf(ss * (1.0f / 512.0f) - m * m + 1e-5f);
}

// tanh-form GELU (max abs err ~3e-4, well under bf16 rounding)
__device__ __forceinline__ float gelu_t(float v) {
  float u = v + 0.044715f * v * v * v;
  float z2 = 1.5957691216f * fabsf(u);
  float t = __expf(-z2);
  float th = 1.0f - 2.0f * t / (1.0f + t);
  th = (u < 0.0f) ? -th : th;
  return 0.5f * v * (1.0f + th);
}

// ---------------- small kernels ----------------

__global__ __launch_bounds__(256) void time_emb_kernel(
    const float* __restrict__ emb, const float* __restrict__ W_emb,
    const float* __restrict__ b_emb, float* __restrict__ t)
{
  int b = blockIdx.x;
  int c = blockIdx.y * 256 + threadIdx.x;
  __shared__ float se[512];
  for (int k = threadIdx.x; k < 512; k += 256) {
    float e = emb[b * 512 + k];
    se[k] = e / (1.0f + expf(-e));
  }
  __syncthreads();
  float acc = b_emb[c];
  for (int k = 0; k < 512; ++k) acc += se[k] * W_emb[k * 512 + c];
  t[b * 512 + c] = acc;
}

// W (Kd x Nd) f32 -> Wt (Nd x Kd) bf16
__global__ void transpose_cast_kernel(const float* __restrict__ W, bf16* __restrict__ Wt,
                                      int Kd, int Nd)
{
  __shared__ float tile[32][33];
  int n0 = blockIdx.x * 32, k0 = blockIdx.y * 32;
  for (int r = threadIdx.y; r < 32; r += 8)
    tile[r][threadIdx.x] = W[(long)(k0 + r) * Nd + n0 + threadIdx.x];
  __syncthreads();
  for (int r = threadIdx.y; r < 32; r += 8)
    Wt[(long)(n0 + r) * Kd + k0 + threadIdx.x] = __float2bfloat16(tile[threadIdx.x][r]);
}

// combined bias+mask table: tbl[h][wtype][i(query) 80][t(key) 80] f32
__global__ __launch_bounds__(256) void bias_mask_kernel(
    const float* __restrict__ btab, float* __restrict__ tbl)
{
  int h = blockIdx.x, wt = blockIdx.y;
  for (int idx = threadIdx.x; idx < 6400; idx += 256) {
    int i = idx / 80, t = idx % 80;
    float v;
    if (t >= 65) v = -1e30f;
    else if (i >= 64 || t == 64) v = 0.0f;
    else {
      int rel = (((i >> 3) - (t >> 3) + 7) * 15) + ((i & 7) - (t & 7) + 7);
      v = btab[rel * HEADS_ + h];
      int rci = (wt & 2) ? (((i >> 3) < 4) ? 1 : 2) : 0;
      int cci = (wt & 1) ? (((i & 7) < 4) ? 1 : 2) : 0;
      int rct = (wt & 2) ? (((t >> 3) < 4) ? 1 : 2) : 0;
      int cct = (wt & 1) ? (((t & 7) < 4) ? 1 : 2) : 0;
      if (rci * 3 + cci != rct * 3 + cct) v -= 100.0f;
    }
    tbl[(h * 4 + wt) * 6400 + idx] = v;
  }
}

// LN1 + cyclic shift + window partition + time-token append -> xw bf16 (66560 x 512)
__global__ __launch_bounds__(256) void ln1_window_kernel(
    const float* __restrict__ x, const float* __restrict__ gamma,
    const float* __restrict__ beta, const float* __restrict__ t,
    bf16* __restrict__ xw)
{
  long r = (long)blockIdx.x * 4 + (threadIdx.x >> 6);   // 0..66559
  int lane = threadIdx.x & 63;
  int wb = (int)(r / NTOK), i = (int)(r % NTOK);
  int b = wb >> 6, w = wb & 63;
  bf16* out = xw + r * 512 + lane * 8;
  if (i == 64) {
    const float* tr = t + b * 512 + lane * 8;
    short8 o;
    #pragma unroll
    for (int e = 0; e < 8; ++e) o[e] = f2s(tr[e]);
    *(short8*)out = o;
    return;
  }
  int wh = w >> 3, ww = w & 7, ih = i >> 3, iw = i & 7;
  int hsrc = ((wh * 8 + ih) + 4) & 63;
  int wsrc = ((ww * 8 + iw) + 4) & 63;
  const float* xr = x + ((long)b * 4096 + hsrc * 64 + wsrc) * 512 + lane * 8;
  float v[8];
  *(f32x4*)&v[0] = *(const f32x4*)xr;
  *(f32x4*)&v[4] = *(const f32x4*)(xr + 4);
  float m, rstd;
  wave_stats512(v, m, rstd);
  const float* g = gamma + lane * 8;
  const float* bt = beta + lane * 8;
  short8 o;
  #pragma unroll
  for (int e = 0; e < 8; ++e) o[e] = f2s((v[e] - m) * rstd * g[e] + bt[e]);
  *(short8*)out = o;
}

// LN2 over x1 rows (65536 x 512) -> bf16 ; one WAVE per row
__global__ __launch_bounds__(256) void ln2_kernel(
    const float* __restrict__ x1, const float* __restrict__ gamma,
    const float* __restrict__ beta, bf16* __restrict__ out)
{
  long r = (long)blockIdx.x * 4 + (threadIdx.x >> 6);
  int lane = threadIdx.x & 63;
  const float* xr = x1 + r * 512 + lane * 8;
  float v[8];
  *(f32x4*)&v[0] = *(const f32x4*)xr;
  *(f32x4*)&v[4] = *(const f32x4*)(xr + 4);
  float m, rstd;
  wave_stats512(v, m, rstd);
  const float* g = gamma + lane * 8;
  const float* bt = beta + lane * 8;
  short8 o;
  #pragma unroll
  for (int e = 0; e < 8; ++e) o[e] = f2s((v[e] - m) * rstd * g[e] + bt[e]);
  *(short8*)(out + r * 512 + lane * 8) = o;
}

// ---------------- 128x256 MFMA GEMM, BK=32, 3-buffer counted-vmcnt pipeline ----
// C = A(MxK) @ Bt(NxK)^T + bias. 512 threads = 8 waves (2M x 4N), per-wave 64x64.
// LDS 72 KiB: lA[3][128*32], lB[3][256*32] -> 2 blocks/CU.
// Depth-2 prefetch: prologue stages tiles 0,1; iteration t waits vmcnt(3)
// (tile t landed, t+1 in flight), raw barrier, ds_read frags(t), stage(t+2),
// MFMA. Buffer (t+2)%3 == (t-1)%3, whose reads finished before this barrier.
// Last iteration waits vmcnt(0). EPI 0: bf16 | 1: gelu->bf16 | 2: proj scatter | 3: f32 +=
template<int EPI>
__global__ __launch_bounds__(512, 4) void gemmk_kernel(
    const bf16* __restrict__ A, const bf16* __restrict__ Bt,
    const float* __restrict__ bias, int N, int K, int nx,
    bf16* __restrict__ outB, float* __restrict__ outF,
    const float* __restrict__ xin, int rowOffset)
{
  __shared__ bf16 lA[3][128 * 32];
  __shared__ bf16 lB[3][256 * 32];
  const int tid = threadIdx.x;
  const int lane = tid & 63, wv = tid >> 6;
  const int wm = wv >> 2, wn = wv & 3;       // 2 x 4
  const int fr = lane & 15, fg = lane >> 4;

  // bijective XCD swizzle (m204)
  const int nwg = gridDim.x, bid = blockIdx.x;
  const int q = nwg >> 3, rr8 = nwg & 7;
  const int xcd = bid & 7, idx = bid >> 3;
  const int sid = (xcd < rr8 ? xcd * (q + 1) : rr8 * (q + 1) + (xcd - rr8) * q) + idx;
  const long row0 = (long)(sid / nx) * 128;
  const long col0 = (long)(sid % nx) * 256;

  // staging geometry: per thread one 16B slot; one instr covers 16 rows
  const int rl = lane >> 2, sp = lane & 3;
  const int s = sp ^ ((rl >> 1) & 3);        // pre-swizzled global slot
  const bf16* gA  = A  + (row0 + wv * 16 + rl) * (long)K + s * 8;
  const bf16* gB0 = Bt + (col0 + wv * 16 + rl) * (long)K + s * 8;
  const bf16* gB1 = Bt + (col0 + 128 + wv * 16 + rl) * (long)K + s * 8;

  f32x4 acc[4][4] = {};
  const int nkt = K >> 5;
  const int swr = (fg ^ ((fr >> 1) & 3)) << 4;   // read-side swizzled slot byte

  auto stage = [&](int buf, int kt) {
    async_lds16(gA + kt, &lA[buf][wv * 512]);
    async_lds16(gB0 + kt, &lB[buf][wv * 512]);
    async_lds16(gB1 + kt, &lB[buf][4096 + wv * 512]);
  };

  stage(0, 0);
  stage(1, 32);

  for (int t = 0; t < nkt; ++t) {
    if (t + 1 < nkt)
      asm volatile("s_waitcnt vmcnt(3)" ::: "memory");   // tile t landed; t+1 in flight
    else
      asm volatile("s_waitcnt vmcnt(0)" ::: "memory");   // last tile: full drain
    __builtin_amdgcn_s_barrier();
    const int buf = t % 3;
    short8 af[4], bfv[4];
    #pragma unroll
    for (int mi = 0; mi < 4; ++mi)
      af[mi] = *(const short8*)((const char*)&lA[buf][0] + (wm * 64 + mi * 16 + fr) * 64 + swr);
    #pragma unroll
    for (int ni = 0; ni < 4; ++ni)
      bfv[ni] = *(const short8*)((const char*)&lB[buf][0] + (wn * 64 + ni * 16 + fr) * 64 + swr);
    if (t + 2 < nkt) stage((t + 2) % 3, (t + 2) << 5);
    __builtin_amdgcn_s_setprio(1);
    #pragma unroll
    for (int mi = 0; mi < 4; ++mi)
      #pragma unroll
      for (int ni = 0; ni < 4; ++ni)
        acc[mi][ni] = __builtin_amdgcn_mfma_f32_16x16x32_bf16(af[mi], bfv[ni], acc[mi][ni], 0, 0, 0);
    __builtin_amdgcn_s_setprio(0);
  }

  // epilogue
  float bs[4];
  #pragma unroll
  for (int ni = 0; ni < 4; ++ni) bs[ni] = bias[col0 + wn * 64 + ni * 16 + fr];
  #pragma unroll
  for (int mi = 0; mi < 4; ++mi) {
    #pragma unroll
    for (int j = 0; j < 4; ++j) {
      long rr = row0 + wm * 64 + mi * 16 + fg * 4 + j;
      if (EPI == 2) {
        int grow = rowOffset + (int)rr;
        int ii = grow % NTOK;
        if (ii == 64) continue;
        int wb = grow / NTOK;
        int b = wb >> 6, w = wb & 63;
        int wh = w >> 3, ww = w & 7, ih = ii >> 3, iw = ii & 7;
        int hh   = ((wh * 8 + ih) + 4) & 63;
        int wcol = ((ww * 8 + iw) + 4) & 63;
        long orow = ((long)b * 4096 + hh * 64 + wcol) * 512;
        #pragma unroll
        for (int ni = 0; ni < 4; ++ni) {
          long o = orow + col0 + wn * 64 + ni * 16 + fr;
          outF[o] = xin[o] + acc[mi][ni][j] + bs[ni];
        }
      } else {
        #pragma unroll
        for (int ni = 0; ni < 4; ++ni) {
          long cc = col0 + wn * 64 + ni * 16 + fr;
          float v = acc[mi][ni][j] + bs[ni];
          if (EPI == 0) {
            outB[rr * N + cc] = __float2bfloat16(v);
          } else if (EPI == 1) {
            outB[rr * N + cc] = __float2bfloat16(gelu_t(v));
          } else {
            long o = rr * N + cc;
            outF[o] = outF[o] + v;
          }
        }
      }
    }
  }
}

// ---------------- MFMA windowed attention: one wave per (window-batch, head) ----
__global__ __launch_bounds__(64, 2) void attn_mfma_kernel(
    const bf16* __restrict__ qkv, bf16* __restrict__ attnO,
    const float* __restrict__ tbl, int wb0)
{
  __shared__ bf16 P[80 * 104];
  const int lwb = blockIdx.x, h = blockIdx.y;
  const int lane = threadIdx.x;
  const int fr = lane & 15, g = lane >> 4;
  const float scale = 0.17677669529663687f;   // 1/sqrt(32)
  const bf16* base = qkv + (long)lwb * 65 * 1536 + h * 32 + g * 8;

  // zero P pad slots (t in [80,104))
  for (int idx = lane; idx < 240; idx += 64) {
    int i = idx / 3, sl = idx % 3;
    *(short8*)&P[i * 104 + 80 + sl * 8] = (short8){0, 0, 0, 0, 0, 0, 0, 0};
  }

  short8 bq[5];
  #pragma unroll
  for (int tn = 0; tn < 5; ++tn) {
    int qr = tn * 16 + fr; qr = qr > 64 ? 64 : qr;
    bq[tn] = *(const short8*)(base + (long)qr * 1536);
  }

  f32x4 acc[5][5];
  #pragma unroll
  for (int tm = 0; tm < 5; ++tm) {
    int kr = tm * 16 + fr; kr = kr > 64 ? 64 : kr;
    short8 ak = *(const short8*)(base + 512 + (long)kr * 1536);
    #pragma unroll
    for (int tn = 0; tn < 5; ++tn)
      acc[tm][tn] = __builtin_amdgcn_mfma_f32_16x16x32_bf16(
          ak, bq[tn], (f32x4){0.0f, 0.0f, 0.0f, 0.0f}, 0, 0, 0);
  }

  const int w = (wb0 + lwb) & 63;
  const int wt = (((w >> 3) == 7) ? 2 : 0) + (((w & 7) == 7) ? 1 : 0);
  const float* tp = tbl + (h * 4 + wt) * 6400;
  #pragma unroll
  for (int tn = 0; tn < 5; ++tn) {
    const int i = tn * 16 + fr;
    const float* ti = tp + i * 80 + g * 4;
    float m = -3.0e38f;
    #pragma unroll
    for (int tm = 0; tm < 5; ++tm) {
      f32x4 bv = *(const f32x4*)(ti + tm * 16);
      #pragma unroll
      for (int r = 0; r < 4; ++r) {
        float sv = fmaf(acc[tm][tn][r], scale, bv[r]);
        acc[tm][tn][r] = sv;
        m = fmaxf(m, sv);
      }
    }
    m = fmaxf(m, __shfl_xor(m, 16));
    m = fmaxf(m, __shfl_xor(m, 32));
    float l = 0.0f;
    #pragma unroll
    for (int tm = 0; tm < 5; ++tm)
      #pragma unroll
      for (int r = 0; r < 4; ++r) {
        float e = __expf(acc[tm][tn][r] - m);
        acc[tm][tn][r] = e;
        l += e;
      }
    l += __shfl_xor(l, 16);
    l += __shfl_xor(l, 32);
    float inv = 1.0f / l;
    #pragma unroll
    for (int tm = 0; tm < 5; ++tm) {
      short4_t pk;
      #pragma unroll
      for (int r = 0; r < 4; ++r) pk[r] = f2s(acc[tm][tn][r] * inv);
      *(short4_t*)&P[i * 104 + tm * 16 + g * 4] = pk;
    }
  }

  const bf16* vbase = qkv + (long)lwb * 65 * 1536 + 1024 + h * 32;
  f32x4 oacc[2][5] = {};
  #pragma unroll
  for (int kt = 0; kt < 3; ++kt) {
    short8 bp[5];
    #pragma unroll
    for (int tn = 0; tn < 5; ++tn)
      bp[tn] = *(const short8*)&P[(tn * 16 + fr) * 104 + kt * 32 + g * 8];
    #pragma unroll
    for (int ma = 0; ma < 2; ++ma) {
      short8 av;
      #pragma unroll
      for (int e = 0; e < 8; ++e) {
        int vr = kt * 32 + g * 8 + e; vr = vr > 64 ? 64 : vr;
        av[e] = *(const short*)(vbase + (long)vr * 1536 + ma * 16 + fr);
      }
      #pragma unroll
      for (int tn = 0; tn < 5; ++tn)
        oacc[ma][tn] = __builtin_amdgcn_mfma_f32_16x16x32_bf16(
            av, bp[tn], oacc[ma][tn], 0, 0, 0);
    }
  }

  #pragma unroll
  for (int tn = 0; tn < 5; ++tn) {
    int i = tn * 16 + fr;
    if (i < 65) {
      bf16* op = attnO + (long)(lwb * 65 + i) * 512 + h * 32 + g * 4;
      #pragma unroll
      for (int ma = 0; ma < 2; ++ma) {
        short4_t o4;
        #pragma unroll
        for (int r = 0; r < 4; ++r) o4[r] = f2s(oacc[ma][tn][r]);
        *(short4_t*)(op + ma * 16) = o4;
      }
    }
  }
}

// ---------------- host ----------------

extern "C" void kernel_launch(void* const* d_in, const int* in_sizes, int n_in,
                              void* d_out, int out_size, void* d_ws, size_t ws_size,
                              hipStream_t stream)
{
  const float* x      = (const float*)d_in[0];
  const float* emb    = (const float*)d_in[1];
  const float* gamma1 = (const float*)d_in[2];
  const float* beta1  = (const float*)d_in[3];
  const float* W_emb  = (const float*)d_in[4];
  const float* b_emb  = (const float*)d_in[5];
  const float* W_qkv  = (const float*)d_in[6];
  const float* b_qkv  = (const float*)d_in[7];
  const float* btab   = (const float*)d_in[8];
  const float* W_proj = (const float*)d_in[9];
  const float* b_proj = (const float*)d_in[10];
  const float* gamma2 = (const float*)d_in[11];
  const float* beta2  = (const float*)d_in[12];
  const float* W1     = (const float*)d_in[13];
  const float* b1     = (const float*)d_in[14];
  const float* W2     = (const float*)d_in[15];
  const float* b2     = (const float*)d_in[16];
  float* out = (float*)d_out;
  (void)n_in; (void)in_sizes; (void)out_size;

  char* ws = (char*)d_ws;
  size_t off = 0;
  auto alloc = [&](size_t bytes) -> char* {
    char* p = ws + off;
    off += (bytes + 255) & ~(size_t)255;
    return p;
  };
  bf16* wt_qkv  = (bf16*)alloc((size_t)1536 * 512 * 2);
  bf16* wt_proj = (bf16*)alloc((size_t)512 * 512 * 2);
  bf16* wt1     = (bf16*)alloc((size_t)2048 * 512 * 2);
  bf16* wt2     = (bf16*)alloc((size_t)512 * 2048 * 2);
  float* tvec   = (float*)alloc((size_t)16 * 512 * 4);
  float* tbl    = (float*)alloc((size_t)16 * 4 * 6400 * 4);

  const size_t sz_xw    = (size_t)TOTROWS * 512 * 2;
  const size_t sz_qkv   = (size_t)TOTROWS * 1536 * 2;
  const size_t sz_attnO = (size_t)TOTROWS * 512 * 2;
  const bool big = ws_size >= off + sz_xw + sz_qkv + sz_attnO + (4u << 20);

  // weight prep (common)
  transpose_cast_kernel<<<dim3(1536 / 32, 512 / 32), dim3(32, 8), 0, stream>>>(W_qkv, wt_qkv, 512, 1536);
  transpose_cast_kernel<<<dim3(512 / 32, 512 / 32),  dim3(32, 8), 0, stream>>>(W_proj, wt_proj, 512, 512);
  transpose_cast_kernel<<<dim3(2048 / 32, 512 / 32), dim3(32, 8), 0, stream>>>(W1, wt1, 512, 2048);
  transpose_cast_kernel<<<dim3(512 / 32, 2048 / 32), dim3(32, 8), 0, stream>>>(W2, wt2, 2048, 512);
  time_emb_kernel<<<dim3(16, 2), 256, 0, stream>>>(emb, W_emb, b_emb, tvec);
  bias_mask_kernel<<<dim3(16, 4), 256, 0, stream>>>(btab, tbl);

  if (big) {
    bf16* xw    = (bf16*)alloc(sz_xw);
    bf16* qkv   = (bf16*)alloc(sz_qkv);
    bf16* attnO = (bf16*)alloc(sz_attnO);
    bf16* ln2b  = xw;          // xw dead after qkv GEMM
    bf16* h     = qkv;         // qkv dead after attention

    ln1_window_kernel<<<TOTROWS / 4, 256, 0, stream>>>(x, gamma1, beta1, tvec, xw);
    // qkv: M=66560, N=1536, K=512 -> grid 6 x 520
    gemmk_kernel<0><<<6 * 520, 512, 0, stream>>>(
        xw, wt_qkv, b_qkv, 1536, 512, 6, qkv, nullptr, nullptr, 0);
    attn_mfma_kernel<<<dim3(NB * NWIN, HEADS_), 64, 0, stream>>>(qkv, attnO, tbl, 0);
    // proj: M=66560, N=512, K=512 -> grid 2 x 520
    gemmk_kernel<2><<<2 * 520, 512, 0, stream>>>(
        attnO, wt_proj, b_proj, 512, 512, 2, nullptr, out, x, 0);
    ln2_kernel<<<65536 / 4, 256, 0, stream>>>(out, gamma2, beta2, ln2b);
    // mlp1: M=65536, N=2048, K=512 -> grid 8 x 512
    gemmk_kernel<1><<<8 * 512, 512, 0, stream>>>(
        ln2b, wt1, b1, 2048, 512, 8, h, nullptr, nullptr, 0);
    // mlp2: M=65536, N=512, K=2048 -> grid 2 x 512
    gemmk_kernel<3><<<2 * 512, 512, 0, stream>>>(
        h, wt2, b2, 512, 2048, 2, nullptr, out, nullptr, 0);
  } else {
    // chunked fallback
    char* regionA = alloc(sz_xw);                     // xw, later ln2b
    bf16* xw   = (bf16*)regionA;
    bf16* ln2b = (bf16*)regionA;
    bf16* qkv_c = (bf16*)alloc((size_t)ATT_CHUNK_ROWS * 1536 * 2);
    char* regionB = alloc(sz_attnO);                  // attnO, later h_c
    bf16* attnO = (bf16*)regionB;
    bf16* h_c   = (bf16*)regionB;

    ln1_window_kernel<<<TOTROWS / 4, 256, 0, stream>>>(x, gamma1, beta1, tvec, xw);
    for (int ac = 0; ac < 8; ++ac) {
      long r0 = (long)ac * ATT_CHUNK_ROWS;
      gemmk_kernel<0><<<6 * 65, 512, 0, stream>>>(
          xw + r0 * 512, wt_qkv, b_qkv, 1536, 512, 6, qkv_c, nullptr, nullptr, 0);
      attn_mfma_kernel<<<dim3(ATT_CHUNK_WB, HEADS_), 64, 0, stream>>>(
          qkv_c, attnO + r0 * 512, tbl, ac * ATT_CHUNK_WB);
    }
    gemmk_kernel<2><<<2 * 520, 512, 0, stream>>>(
        attnO, wt_proj, b_proj, 512, 512, 2, nullptr, out, x, 0);
    ln2_kernel<<<65536 / 4, 256, 0, stream>>>(out, gamma2, beta2, ln2b);
    for (int mc = 0; mc < 4; ++mc) {
      long r0 = (long)mc * 16384;
      gemmk_kernel<1><<<8 * 128, 512, 0, stream>>>(
          ln2b + r0 * 512, wt1, b1, 2048, 512, 8, h_c, nullptr, nullptr, 0);
      gemmk_kernel<3><<<2 * 128, 512, 0, stream>>>(
          h_c, wt2, b2, 512, 2048, 2, nullptr, out + r0 * 512, nullptr, 0);
    }
  }
}